// Round 1
// baseline (6361.103 us; speedup 1.0000x reference)
//
#include <hip/hip_runtime.h>

#define BATCH 32
#define ATOMS 128
#define CCH 3
#define XH 57
#define XW 57
#define OHH 64
#define OWW 64
#define KSEL 2000
#define NPS (ATOMS*XH*XW)      // 415872 per-sample X elements
#define NTOT (BATCH*NPS)       // 13307904
#define RPS (CCH*OHH*OWW)      // 12288 per-sample R elements
#define RTOT (BATCH*RPS)       // 393216
#define CANDCAP 32768

// ---------------------------------------------------------------------------
// R = D(X) - Y   (transposed conv 128->3, out 64x64), f64 accumulation.
// out[b,c,oy,ox] = sum_a sum_{kh,kw} X[b,a,oy-kh,ox-kw] * W[a,c,kh,kw]
// One thread computes 4 consecutive ox outputs. W reads are lane-uniform
// (scalar loads). grid = 32*3*4 blocks of 256.
// ---------------------------------------------------------------------------
__global__ __launch_bounds__(256) void convD_k(const float* __restrict__ X,
    const float* __restrict__ Wg, const float* __restrict__ Y,
    float* __restrict__ R) {
  int bi = blockIdx.x;
  int rowchunk = bi & 3;
  int c = (bi >> 2) % CCH;
  int b = bi / (4 * CCH);
  int tid = threadIdx.x;
  int oy = rowchunk * 16 + (tid >> 4);
  int ox0 = (tid & 15) * 4;
  const float* Xb = X + (size_t)b * NPS;
  double acc0 = 0.0, acc1 = 0.0, acc2 = 0.0, acc3 = 0.0;
  for (int a = 0; a < ATOMS; ++a) {
    const float* Xa = Xb + a * (XH * XW);
    const float* Wa = Wg + (a * CCH + c) * 64;
    for (int kh = 0; kh < 8; ++kh) {
      int iy = oy - kh;
      if ((unsigned)iy >= (unsigned)XH) continue;
      const float* Xrow = Xa + iy * XW;
      double xd[11];
#pragma unroll
      for (int t = 0; t < 11; ++t) {
        int ix = ox0 - 7 + t;
        xd[t] = ((unsigned)ix < (unsigned)XW) ? (double)Xrow[ix] : 0.0;
      }
#pragma unroll
      for (int kw = 0; kw < 8; ++kw) {
        double w = (double)Wa[kh * 8 + kw];
        acc0 += xd[7 - kw] * w;
        acc1 += xd[8 - kw] * w;
        acc2 += xd[9 - kw] * w;
        acc3 += xd[10 - kw] * w;
      }
    }
  }
  size_t ro = ((size_t)(b * CCH + c)) * (OHH * OWW) + (size_t)oy * OWW + ox0;
  R[ro + 0] = (float)(acc0 - (double)Y[ro + 0]);
  R[ro + 1] = (float)(acc1 - (double)Y[ro + 1]);
  R[ro + 2] = (float)(acc2 - (double)Y[ro + 2]);
  R[ro + 3] = (float)(acc3 - (double)Y[ro + 3]);
}

// ---------------------------------------------------------------------------
// HT = Xprev - Dt(R)  (valid conv 3->128, kernel spatially transposed),
// f64 accumulation. out[b,a,y,x] = X[b,a,y,x] - sum_{c,i,j} R[b,c,y+i,x+j]*W[a,c,j,i]
// Block: one (b, group-of-8 atoms, 256-pixel chunk). Whole R[b] (48KB) in LDS.
// grid = 32*16*13 blocks of 256.
// ---------------------------------------------------------------------------
__global__ __launch_bounds__(256) void convDt_k(const float* __restrict__ R,
    const float* __restrict__ Wg, const float* __restrict__ Xprev,
    float* __restrict__ HT) {
  __shared__ float Rl[RPS];
  int bi = blockIdx.x;
  int chunk = bi % 13;
  int ag = (bi / 13) & 15;
  int b = bi / (13 * 16);
  int tid = threadIdx.x;
  for (int e = tid; e < RPS; e += 256) Rl[e] = R[(size_t)b * RPS + e];
  __syncthreads();
  int p = chunk * 256 + tid;
  if (p >= XH * XW) return;
  int y = p / XW, x = p - y * XW;
  int a0 = ag * 8;
  double acc[8] = {0, 0, 0, 0, 0, 0, 0, 0};
  for (int c = 0; c < CCH; ++c) {
    for (int i = 0; i < 8; ++i) {
      const float* rrow = &Rl[c * (OHH * OWW) + (y + i) * OWW + x];
#pragma unroll
      for (int j = 0; j < 8; ++j) {
        double r = (double)rrow[j];
#pragma unroll
        for (int aa = 0; aa < 8; ++aa) {
          // W_D[a, c, j, i]  (permute(0,1,3,2))
          acc[aa] += r * (double)Wg[((a0 + aa) * CCH + c) * 64 + j * 8 + i];
        }
      }
    }
  }
#pragma unroll
  for (int aa = 0; aa < 8; ++aa) {
    size_t xo = ((size_t)(b * ATOMS + a0 + aa)) * (XH * XW) + p;
    HT[xo] = (float)((double)Xprev[xo] - acc[aa]);
  }
}

// ---------------------------------------------------------------------------
// Top-K radix select: level 1 histogram over top 11 bits of abs-bits.
// grid = 32 samples * 32 chunks.
// ---------------------------------------------------------------------------
__global__ __launch_bounds__(256) void hist1_k(const float* __restrict__ HT,
                                               unsigned* __restrict__ g1) {
  __shared__ unsigned h[2048];
  for (int e = threadIdx.x; e < 2048; e += 256) h[e] = 0;
  __syncthreads();
  int s = blockIdx.x >> 5;
  int chunk = blockIdx.x & 31;
  const unsigned* U = (const unsigned*)(HT + (size_t)s * NPS);
  for (int i = chunk * 256 + threadIdx.x; i < NPS; i += 32 * 256) {
    unsigned u = U[i] & 0x7fffffffu;
    atomicAdd(&h[u >> 20], 1u);
  }
  __syncthreads();
  for (int e = threadIdx.x; e < 2048; e += 256)
    if (h[e]) atomicAdd(&g1[s * 2048 + e], h[e]);
}

// Find bin containing rank Kv (descending), output bin and residual rank.
template <int NB>
__global__ __launch_bounds__(256) void find_k(const unsigned* __restrict__ gh,
    const int* __restrict__ Kin, int* __restrict__ Bout, int* __restrict__ Kout) {
  int s = blockIdx.x;
  const unsigned* h = gh + s * NB;
  __shared__ unsigned part[256];
  constexpr int C = NB / 256;
  int t = threadIdx.x;
  unsigned sum = 0;
#pragma unroll
  for (int e = 0; e < C; ++e) sum += h[t * C + e];
  part[t] = sum;
  __syncthreads();
  if (t == 0) {
    int Kv = Kin ? Kin[s] : KSEL;
    unsigned cumBefore = 0;
    int bsel = 0;
    for (int q = 255; q >= 0; --q) {
      unsigned ps = part[q];
      if ((int)(cumBefore + ps) >= Kv) {
        for (int e = q * C + C - 1;; --e) {
          unsigned c2 = cumBefore + h[e];
          if ((int)c2 >= Kv) { bsel = e; break; }
          cumBefore = c2;
        }
        break;
      }
      cumBefore += ps;
    }
    Bout[s] = bsel;
    Kout[s] = Kv - (int)cumBefore;
  }
}

// Level 2: histogram of next 10 bits among elements in bin b1; also gather
// candidate indices (local, within-sample).
__global__ __launch_bounds__(256) void hist2_k(const float* __restrict__ HT,
    const int* __restrict__ b1, unsigned* __restrict__ g2,
    int* __restrict__ cand, int* __restrict__ candcnt) {
  __shared__ unsigned h[1024];
  for (int e = threadIdx.x; e < 1024; e += 256) h[e] = 0;
  __syncthreads();
  int s = blockIdx.x >> 5;
  int chunk = blockIdx.x & 31;
  unsigned pre = (unsigned)b1[s];
  const unsigned* U = (const unsigned*)(HT + (size_t)s * NPS);
  for (int i = chunk * 256 + threadIdx.x; i < NPS; i += 32 * 256) {
    unsigned u = U[i] & 0x7fffffffu;
    if ((u >> 20) == pre) {
      atomicAdd(&h[(u >> 10) & 1023], 1u);
      int pos = atomicAdd(&candcnt[s], 1);
      if (pos < CANDCAP) cand[s * CANDCAP + pos] = i;
    }
  }
  __syncthreads();
  for (int e = threadIdx.x; e < 1024; e += 256)
    if (h[e]) atomicAdd(&g2[s * 1024 + e], h[e]);
}

// Level 3 + tie resolution, one block per sample over the candidate list.
// Produces tau (abs-bits of cutoff) and cutoff index (keep eq iff idx<=cutoff).
__global__ __launch_bounds__(256) void pass3_k(const float* __restrict__ HT,
    const int* __restrict__ cand, const int* __restrict__ candcnt,
    const int* __restrict__ b1, const int* __restrict__ b2,
    const int* __restrict__ k2, unsigned* __restrict__ tau_out,
    int* __restrict__ cutoff_out) {
  int s = blockIdx.x;
  __shared__ unsigned h[1024];
  __shared__ int eqidx[1024];
  __shared__ int eqn;
  __shared__ unsigned tau_sh;
  __shared__ int k3_sh;
  for (int e = threadIdx.x; e < 1024; e += 256) h[e] = 0;
  if (threadIdx.x == 0) eqn = 0;
  __syncthreads();
  int n = candcnt[s];
  if (n > CANDCAP) n = CANDCAP;
  unsigned pre21 = (((unsigned)b1[s]) << 10) | (unsigned)b2[s];
  const unsigned* U = (const unsigned*)(HT + (size_t)s * NPS);
  for (int t = threadIdx.x; t < n; t += 256) {
    int i = cand[s * CANDCAP + t];
    unsigned u = U[i] & 0x7fffffffu;
    if ((u >> 10) == pre21) atomicAdd(&h[u & 1023], 1u);
  }
  __syncthreads();
  if (threadIdx.x == 0) {
    int Kv = k2[s];
    unsigned cumBefore = 0;
    int b3 = 0;
    for (int e = 1023; e >= 0; --e) {
      unsigned c2 = cumBefore + h[e];
      if ((int)c2 >= Kv) { b3 = e; break; }
      cumBefore = c2;
    }
    tau_sh = (pre21 << 10) | (unsigned)b3;
    k3_sh = Kv - (int)cumBefore;
  }
  __syncthreads();
  unsigned tau = tau_sh;
  for (int t = threadIdx.x; t < n; t += 256) {
    int i = cand[s * CANDCAP + t];
    unsigned u = U[i] & 0x7fffffffu;
    if (u == tau) {
      int pos = atomicAdd(&eqn, 1);
      if (pos < 1024) eqidx[pos] = i;
    }
  }
  __syncthreads();
  if (threadIdx.x == 0) {
    int m = eqn < 1024 ? eqn : 1024;
    int k3 = k3_sh;
    int cutoff;
    if (k3 >= m) {
      cutoff = 0x7fffffff;  // keep all eq
    } else {
      // k3-th smallest index among eq list (lax.top_k keeps lowest indices)
      int last = -1;
      for (int r = 0; r < k3; ++r) {
        int mn = 0x7fffffff;
        for (int q = 0; q < m; ++q) {
          int v = eqidx[q];
          if (v > last && v < mn) mn = v;
        }
        last = mn;
      }
      cutoff = last;
    }
    tau_out[s] = tau;
    cutoff_out[s] = cutoff;
  }
}

// Hard-threshold write: keep iff |x| > tau, or |x|==tau and idx <= cutoff.
__global__ __launch_bounds__(256) void write_k(const float* __restrict__ HT,
    const unsigned* __restrict__ tau, const int* __restrict__ cutoff,
    float* __restrict__ Xo) {
  int stride = gridDim.x * 256;
  for (int i = blockIdx.x * 256 + threadIdx.x; i < NTOT; i += stride) {
    int s = i / NPS;
    int il = i - s * NPS;
    float xv = HT[i];
    unsigned u = __float_as_uint(xv) & 0x7fffffffu;
    unsigned tt = tau[s];
    float o = 0.0f;
    if (u > tt || (u == tt && il <= cutoff[s])) o = xv;
    Xo[i] = o;
  }
}

extern "C" void kernel_launch(void* const* d_in, const int* in_sizes, int n_in,
                              void* d_out, int out_size, void* d_ws, size_t ws_size,
                              hipStream_t stream) {
  const float* Y  = (const float*)d_in[0];
  const float* X0 = (const float*)d_in[1];
  const float* Wg = (const float*)d_in[2];
  float* Xout = (float*)d_out;

  float* wsf = (float*)d_ws;
  float* HT   = wsf;                                   // NTOT floats
  float* Rbuf = wsf + NTOT;                            // RTOT floats
  unsigned* g1 = (unsigned*)(Rbuf + RTOT);             // 32*2048
  unsigned* g2 = g1 + 32 * 2048;                       // 32*1024
  int* candcnt = (int*)(g2 + 32 * 1024);               // 32
  int* b1 = candcnt + 32;
  int* k1 = b1 + 32;
  int* b2 = k1 + 32;
  int* k2 = b2 + 32;
  unsigned* tau = (unsigned*)(k2 + 32);
  int* cutoff = (int*)(tau + 32);
  int* cand = cutoff + 32;                             // 32*CANDCAP
  size_t zero_bytes = (size_t)(32 * 2048 + 32 * 1024 + 32) * 4;

  for (int it = 0; it < 3; ++it) {
    const float* Xsrc = (it == 0) ? X0 : (const float*)Xout;
    hipMemsetAsync(g1, 0, zero_bytes, stream);
    convD_k<<<dim3(BATCH * CCH * 4), dim3(256), 0, stream>>>(Xsrc, Wg, Y, Rbuf);
    convDt_k<<<dim3(BATCH * 16 * 13), dim3(256), 0, stream>>>(Rbuf, Wg, Xsrc, HT);
    hist1_k<<<dim3(BATCH * 32), dim3(256), 0, stream>>>(HT, g1);
    find_k<2048><<<dim3(BATCH), dim3(256), 0, stream>>>(g1, (const int*)nullptr, b1, k1);
    hist2_k<<<dim3(BATCH * 32), dim3(256), 0, stream>>>(HT, b1, g2, cand, candcnt);
    find_k<1024><<<dim3(BATCH), dim3(256), 0, stream>>>(g2, k1, b2, k2);
    pass3_k<<<dim3(BATCH), dim3(256), 0, stream>>>(HT, cand, candcnt, b1, b2, k2, tau, cutoff);
    write_k<<<dim3(4096), dim3(256), 0, stream>>>(HT, tau, cutoff, Xout);
  }
}

// Round 2
// 3944.172 us; speedup vs baseline: 1.6128x; 1.6128x over previous
//
#include <hip/hip_runtime.h>

#define BATCH 32
#define ATOMS 128
#define CCH 3
#define XH 57
#define XW 57
#define OHH 64
#define OWW 64
#define KSEL 2000
#define PIX (XH*XW)            // 3249
#define NPS (ATOMS*PIX)        // 415872 per-sample X elements
#define NTOT (BATCH*NPS)       // 13307904
#define RPS (CCH*OHH*OWW)      // 12288 per-sample R elements
#define RTOT (BATCH*RPS)       // 393216
#define CANDCAP 32768
#define NW 24576               // weight elements 128*3*8*8

// ---------------------------------------------------------------------------
// Weight prep (runs once): convert to f64 in two layouts.
// WDd [a][kh][c][kw]  : for convD  -> contiguous 24 doubles per (a,kh)
// Wt2d[c][i][j][a]    : for convDt -> contiguous 8 doubles per (c,i,j,atom-grp)
// ---------------------------------------------------------------------------
__global__ __launch_bounds__(256) void wprep_k(const float* __restrict__ Wg,
    double* __restrict__ WDd, double* __restrict__ Wt2d) {
  int e = blockIdx.x * 256 + threadIdx.x;
  if (e >= NW) return;
  {
    int kw = e & 7; int t = e >> 3; int c = t % 3; t /= 3; int kh = t & 7; int a = t >> 3;
    WDd[e] = (double)Wg[(a*3 + c)*64 + kh*8 + kw];
  }
  {
    int a = e & 127; int t = e >> 7; int j = t & 7; int i = (t >> 3) & 7; int c = t >> 6;
    Wt2d[e] = (double)Wg[(a*3 + c)*64 + j*8 + i];
  }
}

// ---------------------------------------------------------------------------
// R = D(X) - Y   (transposed conv 128->3, out 64x64), f64 accumulation.
// Block = one (b, oy). 4 subgroups x 64 lanes; subgroup g reduces atoms
// [32g,32g+32); lane = ox. LDS f64 cross-subgroup reduction.
// grid = 2048 (XCD-swizzled).
// ---------------------------------------------------------------------------
__global__ __launch_bounds__(256) void convD_k(const float* __restrict__ X,
    const double* __restrict__ WDd, const float* __restrict__ Y,
    float* __restrict__ R) {
  __shared__ double part[4][3][64];
  int p = blockIdx.x;
  int lg = (p & 7) * 256 + (p >> 3);          // bijective: 2048 = 8*256
  int b = lg >> 6, oy = lg & 63;
  int tid = threadIdx.x;
  int ox = tid & 63, g = tid >> 6;

  int col[8]; bool vld[8];
#pragma unroll
  for (int t = 0; t < 8; ++t) {
    int ix = ox - 7 + t;
    vld[t] = (unsigned)ix < (unsigned)XW;
    col[t] = vld[t] ? ix : 0;
  }
  int kh_lo = oy > 56 ? oy - 56 : 0;          // uniform bounds
  int kh_hi = oy < 7 ? oy : 7;

  const float* Xb = X + (size_t)b * NPS;
  double ac0 = 0.0, ac1 = 0.0, ac2 = 0.0;
  for (int a = g * 32; a < g * 32 + 32; ++a) {
    const float* Xa = Xb + a * PIX;
    const double* Wa = WDd + a * 192;
    for (int kh = kh_lo; kh <= kh_hi; ++kh) {
      const float* rowp = Xa + (oy - kh) * XW;
      const double* Wk = Wa + kh * 24;
      double xd[8];
#pragma unroll
      for (int t = 0; t < 8; ++t) {
        float f = rowp[col[t]];
        xd[t] = (double)(vld[t] ? f : 0.0f);
      }
#pragma unroll
      for (int kw = 0; kw < 8; ++kw) {
        ac0 = fma(xd[7 - kw], Wk[kw],      ac0);
        ac1 = fma(xd[7 - kw], Wk[8 + kw],  ac1);
        ac2 = fma(xd[7 - kw], Wk[16 + kw], ac2);
      }
    }
  }
  part[g][0][ox] = ac0;
  part[g][1][ox] = ac1;
  part[g][2][ox] = ac2;
  __syncthreads();
  if (tid < 192) {
    int c = tid >> 6, oxx = tid & 63;
    double s = part[0][c][oxx] + part[1][c][oxx] + part[2][c][oxx] + part[3][c][oxx];
    size_t ro = ((size_t)(b * CCH + c) << 12) + ((size_t)oy << 6) + oxx;
    R[ro] = (float)(s - (double)Y[ro]);
  }
}

// ---------------------------------------------------------------------------
// HT = Xprev - Dt(R), f64. Block = (b, atom-group of 8, 16-row band).
// Thread: lane x (0..63), 4 output rows, 8 atoms -> acc[8][4] in VGPRs.
// R band staged in LDS [3][23][72] (stride-72 pad: no x bounds checks).
// Weights via uniform contiguous s_loads from Wt2d. grid = 2048 (swizzled).
// ---------------------------------------------------------------------------
__global__ __launch_bounds__(256) void convDt_k(const float* __restrict__ R,
    const double* __restrict__ Wt2d, const float* __restrict__ Xprev,
    float* __restrict__ HT) {
  __shared__ float Rl[3][23][72];
  int p = blockIdx.x;
  int lg = (p & 7) * 256 + (p >> 3);
  int b = lg >> 6; int rem = lg & 63; int ag = rem >> 2; int by = rem & 3;
  int row0 = by * 16;
  int tid = threadIdx.x;
  for (int e = tid; e < 3 * 23 * 72; e += 256) {
    int c = e / (23 * 72); int r2 = e - c * (23 * 72);
    int rr = r2 / 72; int cc = r2 - rr * 72;
    int gr = row0 + rr;
    float v = 0.0f;
    if (cc < OWW && gr < OHH)
      v = R[((size_t)(b * CCH + c) << 12) + (gr << 6) + cc];
    Rl[c][rr][cc] = v;
  }
  __syncthreads();
  int x = tid & 63, yg = tid >> 6;
  int yb = yg * 4;
  int a0 = ag * 8;
  double acc[8][4];
#pragma unroll
  for (int aa = 0; aa < 8; ++aa)
#pragma unroll
    for (int ty = 0; ty < 4; ++ty) acc[aa][ty] = 0.0;

  for (int c = 0; c < 3; ++c)
    for (int i = 0; i < 8; ++i) {
#pragma unroll
      for (int j = 0; j < 8; ++j) {
        const double* wp = Wt2d + ((c * 8 + i) * 8 + j) * 128 + a0;
        double r0 = (double)Rl[c][yb + 0 + i][x + j];
        double r1 = (double)Rl[c][yb + 1 + i][x + j];
        double r2 = (double)Rl[c][yb + 2 + i][x + j];
        double r3 = (double)Rl[c][yb + 3 + i][x + j];
#pragma unroll
        for (int aa = 0; aa < 8; ++aa) {
          double w = wp[aa];
          acc[aa][0] = fma(r0, w, acc[aa][0]);
          acc[aa][1] = fma(r1, w, acc[aa][1]);
          acc[aa][2] = fma(r2, w, acc[aa][2]);
          acc[aa][3] = fma(r3, w, acc[aa][3]);
        }
      }
    }
  if (x < XW) {
    int gy0 = row0 + yb;
#pragma unroll
    for (int ty = 0; ty < 4; ++ty) {
      int yy = gy0 + ty;
      if (yy < XH) {
#pragma unroll
        for (int aa = 0; aa < 8; ++aa) {
          size_t xo = (size_t)(b * ATOMS + a0 + aa) * PIX + yy * XW + x;
          HT[xo] = (float)((double)Xprev[xo] - acc[aa][ty]);
        }
      }
    }
  }
}

// ---------------------------------------------------------------------------
// Top-K radix select (unchanged from round 1)
// ---------------------------------------------------------------------------
__global__ __launch_bounds__(256) void hist1_k(const float* __restrict__ HT,
                                               unsigned* __restrict__ g1) {
  __shared__ unsigned h[2048];
  for (int e = threadIdx.x; e < 2048; e += 256) h[e] = 0;
  __syncthreads();
  int s = blockIdx.x >> 5;
  int chunk = blockIdx.x & 31;
  const unsigned* U = (const unsigned*)(HT + (size_t)s * NPS);
  for (int i = chunk * 256 + threadIdx.x; i < NPS; i += 32 * 256) {
    unsigned u = U[i] & 0x7fffffffu;
    atomicAdd(&h[u >> 20], 1u);
  }
  __syncthreads();
  for (int e = threadIdx.x; e < 2048; e += 256)
    if (h[e]) atomicAdd(&g1[s * 2048 + e], h[e]);
}

template <int NB>
__global__ __launch_bounds__(256) void find_k(const unsigned* __restrict__ gh,
    const int* __restrict__ Kin, int* __restrict__ Bout, int* __restrict__ Kout) {
  int s = blockIdx.x;
  const unsigned* h = gh + s * NB;
  __shared__ unsigned part[256];
  constexpr int C = NB / 256;
  int t = threadIdx.x;
  unsigned sum = 0;
#pragma unroll
  for (int e = 0; e < C; ++e) sum += h[t * C + e];
  part[t] = sum;
  __syncthreads();
  if (t == 0) {
    int Kv = Kin ? Kin[s] : KSEL;
    unsigned cumBefore = 0;
    int bsel = 0;
    for (int q = 255; q >= 0; --q) {
      unsigned ps = part[q];
      if ((int)(cumBefore + ps) >= Kv) {
        for (int e = q * C + C - 1;; --e) {
          unsigned c2 = cumBefore + h[e];
          if ((int)c2 >= Kv) { bsel = e; break; }
          cumBefore = c2;
        }
        break;
      }
      cumBefore += ps;
    }
    Bout[s] = bsel;
    Kout[s] = Kv - (int)cumBefore;
  }
}

__global__ __launch_bounds__(256) void hist2_k(const float* __restrict__ HT,
    const int* __restrict__ b1, unsigned* __restrict__ g2,
    int* __restrict__ cand, int* __restrict__ candcnt) {
  __shared__ unsigned h[1024];
  for (int e = threadIdx.x; e < 1024; e += 256) h[e] = 0;
  __syncthreads();
  int s = blockIdx.x >> 5;
  int chunk = blockIdx.x & 31;
  unsigned pre = (unsigned)b1[s];
  const unsigned* U = (const unsigned*)(HT + (size_t)s * NPS);
  for (int i = chunk * 256 + threadIdx.x; i < NPS; i += 32 * 256) {
    unsigned u = U[i] & 0x7fffffffu;
    if ((u >> 20) == pre) {
      atomicAdd(&h[(u >> 10) & 1023], 1u);
      int pos = atomicAdd(&candcnt[s], 1);
      if (pos < CANDCAP) cand[s * CANDCAP + pos] = i;
    }
  }
  __syncthreads();
  for (int e = threadIdx.x; e < 1024; e += 256)
    if (h[e]) atomicAdd(&g2[s * 1024 + e], h[e]);
}

__global__ __launch_bounds__(256) void pass3_k(const float* __restrict__ HT,
    const int* __restrict__ cand, const int* __restrict__ candcnt,
    const int* __restrict__ b1, const int* __restrict__ b2,
    const int* __restrict__ k2, unsigned* __restrict__ tau_out,
    int* __restrict__ cutoff_out) {
  int s = blockIdx.x;
  __shared__ unsigned h[1024];
  __shared__ int eqidx[1024];
  __shared__ int eqn;
  __shared__ unsigned tau_sh;
  __shared__ int k3_sh;
  for (int e = threadIdx.x; e < 1024; e += 256) h[e] = 0;
  if (threadIdx.x == 0) eqn = 0;
  __syncthreads();
  int n = candcnt[s];
  if (n > CANDCAP) n = CANDCAP;
  unsigned pre21 = (((unsigned)b1[s]) << 10) | (unsigned)b2[s];
  const unsigned* U = (const unsigned*)(HT + (size_t)s * NPS);
  for (int t = threadIdx.x; t < n; t += 256) {
    int i = cand[s * CANDCAP + t];
    unsigned u = U[i] & 0x7fffffffu;
    if ((u >> 10) == pre21) atomicAdd(&h[u & 1023], 1u);
  }
  __syncthreads();
  if (threadIdx.x == 0) {
    int Kv = k2[s];
    unsigned cumBefore = 0;
    int b3 = 0;
    for (int e = 1023; e >= 0; --e) {
      unsigned c2 = cumBefore + h[e];
      if ((int)c2 >= Kv) { b3 = e; break; }
      cumBefore = c2;
    }
    tau_sh = (pre21 << 10) | (unsigned)b3;
    k3_sh = Kv - (int)cumBefore;
  }
  __syncthreads();
  unsigned tau = tau_sh;
  for (int t = threadIdx.x; t < n; t += 256) {
    int i = cand[s * CANDCAP + t];
    unsigned u = U[i] & 0x7fffffffu;
    if (u == tau) {
      int pos = atomicAdd(&eqn, 1);
      if (pos < 1024) eqidx[pos] = i;
    }
  }
  __syncthreads();
  if (threadIdx.x == 0) {
    int m = eqn < 1024 ? eqn : 1024;
    int k3 = k3_sh;
    int cutoff;
    if (k3 >= m) {
      cutoff = 0x7fffffff;
    } else {
      int last = -1;
      for (int r = 0; r < k3; ++r) {
        int mn = 0x7fffffff;
        for (int q = 0; q < m; ++q) {
          int v = eqidx[q];
          if (v > last && v < mn) mn = v;
        }
        last = mn;
      }
      cutoff = last;
    }
    tau_out[s] = tau;
    cutoff_out[s] = cutoff;
  }
}

__global__ __launch_bounds__(256) void write_k(const float* __restrict__ HT,
    const unsigned* __restrict__ tau, const int* __restrict__ cutoff,
    float* __restrict__ Xo) {
  int stride = gridDim.x * 256;
  for (int i = blockIdx.x * 256 + threadIdx.x; i < NTOT; i += stride) {
    int s = i / NPS;
    int il = i - s * NPS;
    float xv = HT[i];
    unsigned u = __float_as_uint(xv) & 0x7fffffffu;
    unsigned tt = tau[s];
    float o = 0.0f;
    if (u > tt || (u == tt && il <= cutoff[s])) o = xv;
    Xo[i] = o;
  }
}

extern "C" void kernel_launch(void* const* d_in, const int* in_sizes, int n_in,
                              void* d_out, int out_size, void* d_ws, size_t ws_size,
                              hipStream_t stream) {
  const float* Y  = (const float*)d_in[0];
  const float* X0 = (const float*)d_in[1];
  const float* Wg = (const float*)d_in[2];
  float* Xout = (float*)d_out;

  double* WDd  = (double*)d_ws;                        // NW doubles
  double* Wt2d = WDd + NW;                             // NW doubles
  float* HT   = (float*)(Wt2d + NW);                   // NTOT floats
  float* Rbuf = HT + NTOT;                             // RTOT floats
  unsigned* g1 = (unsigned*)(Rbuf + RTOT);             // 32*2048
  unsigned* g2 = g1 + 32 * 2048;                       // 32*1024
  int* candcnt = (int*)(g2 + 32 * 1024);               // 32
  int* b1 = candcnt + 32;
  int* k1 = b1 + 32;
  int* b2 = k1 + 32;
  int* k2 = b2 + 32;
  unsigned* tau = (unsigned*)(k2 + 32);
  int* cutoff = (int*)(tau + 32);
  int* cand = cutoff + 32;                             // 32*CANDCAP
  size_t zero_bytes = (size_t)(32 * 2048 + 32 * 1024 + 32) * 4;

  wprep_k<<<dim3((NW + 255) / 256), dim3(256), 0, stream>>>(Wg, WDd, Wt2d);

  for (int it = 0; it < 3; ++it) {
    const float* Xsrc = (it == 0) ? X0 : (const float*)Xout;
    hipMemsetAsync(g1, 0, zero_bytes, stream);
    convD_k<<<dim3(2048), dim3(256), 0, stream>>>(Xsrc, WDd, Y, Rbuf);
    convDt_k<<<dim3(2048), dim3(256), 0, stream>>>(Rbuf, Wt2d, Xsrc, HT);
    hist1_k<<<dim3(BATCH * 32), dim3(256), 0, stream>>>(HT, g1);
    find_k<2048><<<dim3(BATCH), dim3(256), 0, stream>>>(g1, (const int*)nullptr, b1, k1);
    hist2_k<<<dim3(BATCH * 32), dim3(256), 0, stream>>>(HT, b1, g2, cand, candcnt);
    find_k<1024><<<dim3(BATCH), dim3(256), 0, stream>>>(g2, k1, b2, k2);
    pass3_k<<<dim3(BATCH), dim3(256), 0, stream>>>(HT, cand, candcnt, b1, b2, k2, tau, cutoff);
    write_k<<<dim3(4096), dim3(256), 0, stream>>>(HT, tau, cutoff, Xout);
  }
}

// Round 3
// 3450.574 us; speedup vs baseline: 1.8435x; 1.1430x over previous
//
#include <hip/hip_runtime.h>

#define BATCH 32
#define ATOMS 128
#define CCH 3
#define XH 57
#define XW 57
#define OHH 64
#define OWW 64
#define KSEL 2000
#define PIX (XH*XW)            // 3249
#define NPS (ATOMS*PIX)        // 415872 per-sample X elements
#define NTOT (BATCH*NPS)       // 13307904
#define RPS (CCH*OHH*OWW)      // 12288 per-sample R elements
#define RTOT (BATCH*RPS)       // 393216
#define CANDCAP 32768
#define NW 24576               // weight elements 128*3*8*8

// ---------------------------------------------------------------------------
// Weight prep (runs once): convert to f64 in two layouts.
// WDd [a][kh][c][kw]  : for dense convD
// Wt2d[c][i][j][a]    : for convDt
// ---------------------------------------------------------------------------
__global__ __launch_bounds__(256) void wprep_k(const float* __restrict__ Wg,
    double* __restrict__ WDd, double* __restrict__ Wt2d) {
  int e = blockIdx.x * 256 + threadIdx.x;
  if (e >= NW) return;
  {
    int kw = e & 7; int t = e >> 3; int c = t % 3; t /= 3; int kh = t & 7; int a = t >> 3;
    WDd[e] = (double)Wg[(a*3 + c)*64 + kh*8 + kw];
  }
  {
    int a = e & 127; int t = e >> 7; int j = t & 7; int i = (t >> 3) & 7; int c = t >> 6;
    Wt2d[e] = (double)Wg[(a*3 + c)*64 + j*8 + i];
  }
}

// ---------------------------------------------------------------------------
// DENSE R = D(X) - Y (iteration 0 only). Block = (b, 4-row output band).
// 4 waves x 32 atoms each; X staged in LDS (16 atoms/chunk, 11 rows,
// zero-padded width 72 -> no boundary selects). Lane = ox. LDS f64 reduce.
// grid = 512 (XCD-swizzled).
// ---------------------------------------------------------------------------
__global__ __launch_bounds__(256) void convD_k(const float* __restrict__ X,
    const double* __restrict__ WDd, const float* __restrict__ Y,
    float* __restrict__ R) {
  __shared__ float Xs[16][11][72];            // 50688 B, [ai][r][xcol+7]
  __shared__ double part[4][3][4][64];        // 24576 B
  int p = blockIdx.x;
  int lg = (p & 7) * 64 + (p >> 3);           // bijective: 512 = 8*64
  int b = lg >> 4;
  int row0 = (lg & 15) * 4;                   // output rows row0..row0+3
  int tid = threadIdx.x;
  int ox = tid & 63;
  int wv = __builtin_amdgcn_readfirstlane(tid >> 6);  // wave id, SGPR
  const float* Xb = X + (size_t)b * NPS;

  double acc[4][3];
#pragma unroll
  for (int ty = 0; ty < 4; ++ty)
#pragma unroll
    for (int c = 0; c < 3; ++c) acc[ty][c] = 0.0;

  for (int ch = 0; ch < 8; ++ch) {
    __syncthreads();
    // stage 16 atoms (4 per wave-group): ai -> a = (ai>>2)*32 + ch*4 + (ai&3)
    for (int e = tid; e < 16 * 11 * 72; e += 256) {
      int ai = e / 792; int rem = e - ai * 792;
      int r = rem / 72; int s = rem - r * 72;
      int gy = row0 - 7 + r;
      int xcol = s - 7;
      int a = ((ai >> 2) << 5) + ch * 4 + (ai & 3);
      float v = 0.0f;
      if ((unsigned)xcol < (unsigned)XW && (unsigned)gy < (unsigned)XH)
        v = Xb[a * PIX + gy * XW + xcol];
      Xs[ai][r][s] = v;
    }
    __syncthreads();
    for (int j = 0; j < 4; ++j) {
      int ai = (wv << 2) + j;
      int a  = (wv << 5) + ch * 4 + j;
      const double* Wa = WDd + a * 192;       // [kh][c][kw]
#pragma unroll
      for (int r = 0; r < 11; ++r) {
        int gy = row0 - 7 + r;
        if ((unsigned)gy >= (unsigned)XH) continue;   // uniform
        double xd[8];
#pragma unroll
        for (int t = 0; t < 8; ++t) xd[t] = (double)Xs[ai][r][ox + t];
#pragma unroll
        for (int ty = 0; ty < 4; ++ty) {
          int kh = ty + 7 - r;
          if ((unsigned)kh < 8u) {
            const double* Wk = Wa + kh * 24;
#pragma unroll
            for (int kw = 0; kw < 8; ++kw) {
              acc[ty][0] = fma(xd[7 - kw], Wk[kw],      acc[ty][0]);
              acc[ty][1] = fma(xd[7 - kw], Wk[8 + kw],  acc[ty][1]);
              acc[ty][2] = fma(xd[7 - kw], Wk[16 + kw], acc[ty][2]);
            }
          }
        }
      }
    }
  }
#pragma unroll
  for (int ty = 0; ty < 4; ++ty)
#pragma unroll
    for (int c = 0; c < 3; ++c) part[wv][c][ty][ox] = acc[ty][c];
  __syncthreads();
  for (int e = tid; e < 3 * 4 * 64; e += 256) {
    int c = e >> 8; int rem = e & 255; int ty = rem >> 6; int oxx = rem & 63;
    double s = part[0][c][ty][oxx] + part[1][c][ty][oxx] +
               part[2][c][ty][oxx] + part[3][c][ty][oxx];
    int oy = row0 + ty;
    size_t ro = ((size_t)(b * CCH + c) << 12) + ((size_t)oy << 6) + oxx;
    R[ro] = (float)(s - (double)Y[ro]);
  }
}

// ---------------------------------------------------------------------------
// SPARSE R = D(X) - Y (iterations 1,2). X has exactly KSEL nz per sample
// (idx,val lists from write_k). Block = (sample, c). Scatter into LDS f64
// tile [64][64] via ds f64 atomics; W[:,c,:,:] staged f64 in LDS.
// Lane layout: 8 nz-slots x 8 kw. No bounds checks (y+kh<=63, x+kw<=63).
// ---------------------------------------------------------------------------
__global__ __launch_bounds__(256) void convD_sparse_k(const float* __restrict__ Wg,
    const int* __restrict__ nzidx, const float* __restrict__ nzval,
    const float* __restrict__ Y, float* __restrict__ R) {
  __shared__ double accd[4096];      // 32 KB  [oy][ox]
  __shared__ double Wc[8192];        // 64 KB  [a][kh][kw]
  __shared__ int   li[KSEL];
  __shared__ float lv[KSEL];
  int s = blockIdx.x / 3;
  int c = blockIdx.x % 3;
  int tid = threadIdx.x;
  for (int e = tid; e < 4096; e += 256) accd[e] = 0.0;
  for (int e = tid; e < 8192; e += 256) {
    int a = e >> 6, k2 = e & 63;
    Wc[e] = (double)Wg[(a * 3 + c) * 64 + k2];
  }
  for (int e = tid; e < KSEL; e += 256) {
    li[e] = nzidx[s * KSEL + e];
    lv[e] = nzval[s * KSEL + e];
  }
  __syncthreads();
  int lane = tid & 63, wv = tid >> 6;
  int sub = lane >> 3;               // nz slot within wave
  int kw  = lane & 7;
  for (int base = wv * 8; base < KSEL; base += 32) {   // KSEL % 8 == 0
    int e = base + sub;
    int idx = li[e];
    double val = (double)lv[e];
    int a = (int)((unsigned)idx / 3249u);
    int pp = idx - a * 3249;
    int y = (int)((unsigned)pp / 57u);
    int x = pp - y * 57;
    int rbase = (y << 6) + x + kw;
    const double* wp = Wc + (a << 6) + kw;
#pragma unroll
    for (int kh = 0; kh < 8; ++kh) {
      __hip_atomic_fetch_add(&accd[rbase + (kh << 6)], val * wp[kh << 3],
                             __ATOMIC_RELAXED, __HIP_MEMORY_SCOPE_WORKGROUP);
    }
  }
  __syncthreads();
  const float* Yb = Y + ((size_t)(s * CCH + c) << 12);
  float* Rb = R + ((size_t)(s * CCH + c) << 12);
  for (int e = tid; e < 4096; e += 256)
    Rb[e] = (float)(accd[e] - (double)Yb[e]);
}

// ---------------------------------------------------------------------------
// HT = Xprev - Dt(R), f64 (unchanged from round 2).
// ---------------------------------------------------------------------------
__global__ __launch_bounds__(256) void convDt_k(const float* __restrict__ R,
    const double* __restrict__ Wt2d, const float* __restrict__ Xprev,
    float* __restrict__ HT) {
  __shared__ float Rl[3][23][72];
  int p = blockIdx.x;
  int lg = (p & 7) * 256 + (p >> 3);
  int b = lg >> 6; int rem = lg & 63; int ag = rem >> 2; int by = rem & 3;
  int row0 = by * 16;
  int tid = threadIdx.x;
  for (int e = tid; e < 3 * 23 * 72; e += 256) {
    int c = e / (23 * 72); int r2 = e - c * (23 * 72);
    int rr = r2 / 72; int cc = r2 - rr * 72;
    int gr = row0 + rr;
    float v = 0.0f;
    if (cc < OWW && gr < OHH)
      v = R[((size_t)(b * CCH + c) << 12) + (gr << 6) + cc];
    Rl[c][rr][cc] = v;
  }
  __syncthreads();
  int x = tid & 63, yg = tid >> 6;
  int yb = yg * 4;
  int a0 = ag * 8;
  double acc[8][4];
#pragma unroll
  for (int aa = 0; aa < 8; ++aa)
#pragma unroll
    for (int ty = 0; ty < 4; ++ty) acc[aa][ty] = 0.0;

  for (int c = 0; c < 3; ++c)
    for (int i = 0; i < 8; ++i) {
#pragma unroll
      for (int j = 0; j < 8; ++j) {
        const double* wp = Wt2d + ((c * 8 + i) * 8 + j) * 128 + a0;
        double r0 = (double)Rl[c][yb + 0 + i][x + j];
        double r1 = (double)Rl[c][yb + 1 + i][x + j];
        double r2 = (double)Rl[c][yb + 2 + i][x + j];
        double r3 = (double)Rl[c][yb + 3 + i][x + j];
#pragma unroll
        for (int aa = 0; aa < 8; ++aa) {
          double w = wp[aa];
          acc[aa][0] = fma(r0, w, acc[aa][0]);
          acc[aa][1] = fma(r1, w, acc[aa][1]);
          acc[aa][2] = fma(r2, w, acc[aa][2]);
          acc[aa][3] = fma(r3, w, acc[aa][3]);
        }
      }
    }
  if (x < XW) {
    int gy0 = row0 + yb;
#pragma unroll
    for (int ty = 0; ty < 4; ++ty) {
      int yy = gy0 + ty;
      if (yy < XH) {
#pragma unroll
        for (int aa = 0; aa < 8; ++aa) {
          size_t xo = (size_t)(b * ATOMS + a0 + aa) * PIX + yy * XW + x;
          HT[xo] = (float)((double)Xprev[xo] - acc[aa][ty]);
        }
      }
    }
  }
}

// ---------------------------------------------------------------------------
// Top-K radix select (unchanged) + write_k now emits nz list.
// ---------------------------------------------------------------------------
__global__ __launch_bounds__(256) void hist1_k(const float* __restrict__ HT,
                                               unsigned* __restrict__ g1) {
  __shared__ unsigned h[2048];
  for (int e = threadIdx.x; e < 2048; e += 256) h[e] = 0;
  __syncthreads();
  int s = blockIdx.x >> 5;
  int chunk = blockIdx.x & 31;
  const unsigned* U = (const unsigned*)(HT + (size_t)s * NPS);
  for (int i = chunk * 256 + threadIdx.x; i < NPS; i += 32 * 256) {
    unsigned u = U[i] & 0x7fffffffu;
    atomicAdd(&h[u >> 20], 1u);
  }
  __syncthreads();
  for (int e = threadIdx.x; e < 2048; e += 256)
    if (h[e]) atomicAdd(&g1[s * 2048 + e], h[e]);
}

template <int NB>
__global__ __launch_bounds__(256) void find_k(const unsigned* __restrict__ gh,
    const int* __restrict__ Kin, int* __restrict__ Bout, int* __restrict__ Kout) {
  int s = blockIdx.x;
  const unsigned* h = gh + s * NB;
  __shared__ unsigned part[256];
  constexpr int C = NB / 256;
  int t = threadIdx.x;
  unsigned sum = 0;
#pragma unroll
  for (int e = 0; e < C; ++e) sum += h[t * C + e];
  part[t] = sum;
  __syncthreads();
  if (t == 0) {
    int Kv = Kin ? Kin[s] : KSEL;
    unsigned cumBefore = 0;
    int bsel = 0;
    for (int q = 255; q >= 0; --q) {
      unsigned ps = part[q];
      if ((int)(cumBefore + ps) >= Kv) {
        for (int e = q * C + C - 1;; --e) {
          unsigned c2 = cumBefore + h[e];
          if ((int)c2 >= Kv) { bsel = e; break; }
          cumBefore = c2;
        }
        break;
      }
      cumBefore += ps;
    }
    Bout[s] = bsel;
    Kout[s] = Kv - (int)cumBefore;
  }
}

__global__ __launch_bounds__(256) void hist2_k(const float* __restrict__ HT,
    const int* __restrict__ b1, unsigned* __restrict__ g2,
    int* __restrict__ cand, int* __restrict__ candcnt) {
  __shared__ unsigned h[1024];
  for (int e = threadIdx.x; e < 1024; e += 256) h[e] = 0;
  __syncthreads();
  int s = blockIdx.x >> 5;
  int chunk = blockIdx.x & 31;
  unsigned pre = (unsigned)b1[s];
  const unsigned* U = (const unsigned*)(HT + (size_t)s * NPS);
  for (int i = chunk * 256 + threadIdx.x; i < NPS; i += 32 * 256) {
    unsigned u = U[i] & 0x7fffffffu;
    if ((u >> 20) == pre) {
      atomicAdd(&h[(u >> 10) & 1023], 1u);
      int pos = atomicAdd(&candcnt[s], 1);
      if (pos < CANDCAP) cand[s * CANDCAP + pos] = i;
    }
  }
  __syncthreads();
  for (int e = threadIdx.x; e < 1024; e += 256)
    if (h[e]) atomicAdd(&g2[s * 1024 + e], h[e]);
}

__global__ __launch_bounds__(256) void pass3_k(const float* __restrict__ HT,
    const int* __restrict__ cand, const int* __restrict__ candcnt,
    const int* __restrict__ b1, const int* __restrict__ b2,
    const int* __restrict__ k2, unsigned* __restrict__ tau_out,
    int* __restrict__ cutoff_out) {
  int s = blockIdx.x;
  __shared__ unsigned h[1024];
  __shared__ int eqidx[1024];
  __shared__ int eqn;
  __shared__ unsigned tau_sh;
  __shared__ int k3_sh;
  for (int e = threadIdx.x; e < 1024; e += 256) h[e] = 0;
  if (threadIdx.x == 0) eqn = 0;
  __syncthreads();
  int n = candcnt[s];
  if (n > CANDCAP) n = CANDCAP;
  unsigned pre21 = (((unsigned)b1[s]) << 10) | (unsigned)b2[s];
  const unsigned* U = (const unsigned*)(HT + (size_t)s * NPS);
  for (int t = threadIdx.x; t < n; t += 256) {
    int i = cand[s * CANDCAP + t];
    unsigned u = U[i] & 0x7fffffffu;
    if ((u >> 10) == pre21) atomicAdd(&h[u & 1023], 1u);
  }
  __syncthreads();
  if (threadIdx.x == 0) {
    int Kv = k2[s];
    unsigned cumBefore = 0;
    int b3 = 0;
    for (int e = 1023; e >= 0; --e) {
      unsigned c2 = cumBefore + h[e];
      if ((int)c2 >= Kv) { b3 = e; break; }
      cumBefore = c2;
    }
    tau_sh = (pre21 << 10) | (unsigned)b3;
    k3_sh = Kv - (int)cumBefore;
  }
  __syncthreads();
  unsigned tau = tau_sh;
  for (int t = threadIdx.x; t < n; t += 256) {
    int i = cand[s * CANDCAP + t];
    unsigned u = U[i] & 0x7fffffffu;
    if (u == tau) {
      int pos = atomicAdd(&eqn, 1);
      if (pos < 1024) eqidx[pos] = i;
    }
  }
  __syncthreads();
  if (threadIdx.x == 0) {
    int m = eqn < 1024 ? eqn : 1024;
    int k3 = k3_sh;
    int cutoff;
    if (k3 >= m) {
      cutoff = 0x7fffffff;
    } else {
      int last = -1;
      for (int r = 0; r < k3; ++r) {
        int mn = 0x7fffffff;
        for (int q = 0; q < m; ++q) {
          int v = eqidx[q];
          if (v > last && v < mn) mn = v;
        }
        last = mn;
      }
      cutoff = last;
    }
    tau_out[s] = tau;
    cutoff_out[s] = cutoff;
  }
}

__global__ __launch_bounds__(256) void write_k(const float* __restrict__ HT,
    const unsigned* __restrict__ tau, const int* __restrict__ cutoff,
    float* __restrict__ Xo, int* __restrict__ nzidx, float* __restrict__ nzval,
    int* __restrict__ nzcnt) {
  int stride = gridDim.x * 256;
  for (int i = blockIdx.x * 256 + threadIdx.x; i < NTOT; i += stride) {
    int s = i / NPS;
    int il = i - s * NPS;
    float xv = HT[i];
    unsigned u = __float_as_uint(xv) & 0x7fffffffu;
    unsigned tt = tau[s];
    float o = 0.0f;
    if (u > tt || (u == tt && il <= cutoff[s])) {
      o = xv;
      int pos = atomicAdd(&nzcnt[s], 1);
      if (pos < KSEL) { nzidx[s * KSEL + pos] = il; nzval[s * KSEL + pos] = xv; }
    }
    Xo[i] = o;
  }
}

extern "C" void kernel_launch(void* const* d_in, const int* in_sizes, int n_in,
                              void* d_out, int out_size, void* d_ws, size_t ws_size,
                              hipStream_t stream) {
  const float* Y  = (const float*)d_in[0];
  const float* X0 = (const float*)d_in[1];
  const float* Wg = (const float*)d_in[2];
  float* Xout = (float*)d_out;

  double* WDd  = (double*)d_ws;                        // NW doubles
  double* Wt2d = WDd + NW;                             // NW doubles
  float* HT   = (float*)(Wt2d + NW);                   // NTOT floats
  float* Rbuf = HT + NTOT;                             // RTOT floats
  unsigned* g1 = (unsigned*)(Rbuf + RTOT);             // 32*2048
  unsigned* g2 = g1 + 32 * 2048;                       // 32*1024
  int* candcnt = (int*)(g2 + 32 * 1024);               // 32
  int* nzcnt = candcnt + 32;                           // 32
  int* b1 = nzcnt + 32;
  int* k1 = b1 + 32;
  int* b2 = k1 + 32;
  int* k2 = b2 + 32;
  unsigned* tau = (unsigned*)(k2 + 32);
  int* cutoff = (int*)(tau + 32);
  int* cand = cutoff + 32;                             // 32*CANDCAP
  int* nzidx = cand + 32 * CANDCAP;                    // 32*KSEL
  float* nzval = (float*)(nzidx + 32 * KSEL);          // 32*KSEL
  size_t zero_bytes = (size_t)(32 * 2048 + 32 * 1024 + 32 + 32) * 4;

  wprep_k<<<dim3((NW + 255) / 256), dim3(256), 0, stream>>>(Wg, WDd, Wt2d);

  for (int it = 0; it < 3; ++it) {
    const float* Xsrc = (it == 0) ? X0 : (const float*)Xout;
    hipMemsetAsync(g1, 0, zero_bytes, stream);  // zeroes g1,g2,candcnt,nzcnt
    if (it == 0) {
      convD_k<<<dim3(512), dim3(256), 0, stream>>>(Xsrc, WDd, Y, Rbuf);
    } else {
      convD_sparse_k<<<dim3(BATCH * CCH), dim3(256), 0, stream>>>(
          Wg, nzidx, nzval, Y, Rbuf);
    }
    convDt_k<<<dim3(2048), dim3(256), 0, stream>>>(Rbuf, Wt2d, Xsrc, HT);
    hist1_k<<<dim3(BATCH * 32), dim3(256), 0, stream>>>(HT, g1);
    find_k<2048><<<dim3(BATCH), dim3(256), 0, stream>>>(g1, (const int*)nullptr, b1, k1);
    hist2_k<<<dim3(BATCH * 32), dim3(256), 0, stream>>>(HT, b1, g2, cand, candcnt);
    find_k<1024><<<dim3(BATCH), dim3(256), 0, stream>>>(g2, k1, b2, k2);
    pass3_k<<<dim3(BATCH), dim3(256), 0, stream>>>(HT, cand, candcnt, b1, b2, k2, tau, cutoff);
    write_k<<<dim3(4096), dim3(256), 0, stream>>>(HT, tau, cutoff, Xout,
                                                  nzidx, nzval, nzcnt);
  }
}

// Round 4
// 1947.748 us; speedup vs baseline: 3.2659x; 1.7716x over previous
//
#include <hip/hip_runtime.h>

#define BATCH 32
#define ATOMS 128
#define CCH 3
#define XH 57
#define XW 57
#define OHH 64
#define OWW 64
#define KSEL 2000
#define PIX (XH*XW)            // 3249
#define NPS (ATOMS*PIX)        // 415872 per-sample X elements
#define NTOT (BATCH*NPS)       // 13307904
#define RPS (CCH*OHH*OWW)      // 12288 per-sample R elements
#define RTOT (BATCH*RPS)       // 393216
#define CANDCAP 32768
#define NW 24576               // weight elements 128*3*8*8

// ---------------------------------------------------------------------------
// Weight prep (runs once): convert to f64 in two layouts.
// WDd [a][kh][c][kw]  : for dense convD
// Wt2d[c][i][j][a]    : for convDt
// ---------------------------------------------------------------------------
__global__ __launch_bounds__(256) void wprep_k(const float* __restrict__ Wg,
    double* __restrict__ WDd, double* __restrict__ Wt2d) {
  int e = blockIdx.x * 256 + threadIdx.x;
  if (e >= NW) return;
  {
    int kw = e & 7; int t = e >> 3; int c = t % 3; t /= 3; int kh = t & 7; int a = t >> 3;
    WDd[e] = (double)Wg[(a*3 + c)*64 + kh*8 + kw];
  }
  {
    int a = e & 127; int t = e >> 7; int j = t & 7; int i = (t >> 3) & 7; int c = t >> 6;
    Wt2d[e] = (double)Wg[(a*3 + c)*64 + j*8 + i];
  }
}

// ---------------------------------------------------------------------------
// DENSE R = D(X) - Y (iteration 0 only). Unchanged from round 3.
// ---------------------------------------------------------------------------
__global__ __launch_bounds__(256) void convD_k(const float* __restrict__ X,
    const double* __restrict__ WDd, const float* __restrict__ Y,
    float* __restrict__ R) {
  __shared__ float Xs[16][11][72];
  __shared__ double part[4][3][4][64];
  int p = blockIdx.x;
  int lg = (p & 7) * 64 + (p >> 3);           // bijective: 512 = 8*64
  int b = lg >> 4;
  int row0 = (lg & 15) * 4;
  int tid = threadIdx.x;
  int ox = tid & 63;
  int wv = __builtin_amdgcn_readfirstlane(tid >> 6);
  const float* Xb = X + (size_t)b * NPS;

  double acc[4][3];
#pragma unroll
  for (int ty = 0; ty < 4; ++ty)
#pragma unroll
    for (int c = 0; c < 3; ++c) acc[ty][c] = 0.0;

  for (int ch = 0; ch < 8; ++ch) {
    __syncthreads();
    for (int e = tid; e < 16 * 11 * 72; e += 256) {
      int ai = e / 792; int rem = e - ai * 792;
      int r = rem / 72; int s = rem - r * 72;
      int gy = row0 - 7 + r;
      int xcol = s - 7;
      int a = ((ai >> 2) << 5) + ch * 4 + (ai & 3);
      float v = 0.0f;
      if ((unsigned)xcol < (unsigned)XW && (unsigned)gy < (unsigned)XH)
        v = Xb[a * PIX + gy * XW + xcol];
      Xs[ai][r][s] = v;
    }
    __syncthreads();
    for (int j = 0; j < 4; ++j) {
      int ai = (wv << 2) + j;
      int a  = (wv << 5) + ch * 4 + j;
      const double* Wa = WDd + a * 192;
#pragma unroll
      for (int r = 0; r < 11; ++r) {
        int gy = row0 - 7 + r;
        if ((unsigned)gy >= (unsigned)XH) continue;
        double xd[8];
#pragma unroll
        for (int t = 0; t < 8; ++t) xd[t] = (double)Xs[ai][r][ox + t];
#pragma unroll
        for (int ty = 0; ty < 4; ++ty) {
          int kh = ty + 7 - r;
          if ((unsigned)kh < 8u) {
            const double* Wk = Wa + kh * 24;
#pragma unroll
            for (int kw = 0; kw < 8; ++kw) {
              acc[ty][0] = fma(xd[7 - kw], Wk[kw],      acc[ty][0]);
              acc[ty][1] = fma(xd[7 - kw], Wk[8 + kw],  acc[ty][1]);
              acc[ty][2] = fma(xd[7 - kw], Wk[16 + kw], acc[ty][2]);
            }
          }
        }
      }
    }
  }
#pragma unroll
  for (int ty = 0; ty < 4; ++ty)
#pragma unroll
    for (int c = 0; c < 3; ++c) part[wv][c][ty][ox] = acc[ty][c];
  __syncthreads();
  for (int e = tid; e < 3 * 4 * 64; e += 256) {
    int c = e >> 8; int rem = e & 255; int ty = rem >> 6; int oxx = rem & 63;
    double s = part[0][c][ty][oxx] + part[1][c][ty][oxx] +
               part[2][c][ty][oxx] + part[3][c][ty][oxx];
    int oy = row0 + ty;
    size_t ro = ((size_t)(b * CCH + c) << 12) + ((size_t)oy << 6) + oxx;
    R[ro] = (float)(s - (double)Y[ro]);
  }
}

// ---------------------------------------------------------------------------
// SPARSE R = D(X) - Y (iterations 1,2). Unchanged from round 3.
// ---------------------------------------------------------------------------
__global__ __launch_bounds__(256) void convD_sparse_k(const float* __restrict__ Wg,
    const int* __restrict__ nzidx, const float* __restrict__ nzval,
    const float* __restrict__ Y, float* __restrict__ R) {
  __shared__ double accd[4096];
  __shared__ double Wc[8192];
  __shared__ int   li[KSEL];
  __shared__ float lv[KSEL];
  int s = blockIdx.x / 3;
  int c = blockIdx.x % 3;
  int tid = threadIdx.x;
  for (int e = tid; e < 4096; e += 256) accd[e] = 0.0;
  for (int e = tid; e < 8192; e += 256) {
    int a = e >> 6, k2 = e & 63;
    Wc[e] = (double)Wg[(a * 3 + c) * 64 + k2];
  }
  for (int e = tid; e < KSEL; e += 256) {
    li[e] = nzidx[s * KSEL + e];
    lv[e] = nzval[s * KSEL + e];
  }
  __syncthreads();
  int lane = tid & 63, wv = tid >> 6;
  int sub = lane >> 3;
  int kw  = lane & 7;
  for (int base = wv * 8; base < KSEL; base += 32) {
    int e = base + sub;
    int idx = li[e];
    double val = (double)lv[e];
    int a = (int)((unsigned)idx / 3249u);
    int pp = idx - a * 3249;
    int y = (int)((unsigned)pp / 57u);
    int x = pp - y * 57;
    int rbase = (y << 6) + x + kw;
    const double* wp = Wc + (a << 6) + kw;
#pragma unroll
    for (int kh = 0; kh < 8; ++kh) {
      __hip_atomic_fetch_add(&accd[rbase + (kh << 6)], val * wp[kh << 3],
                             __ATOMIC_RELAXED, __HIP_MEMORY_SCOPE_WORKGROUP);
    }
  }
  __syncthreads();
  const float* Yb = Y + ((size_t)(s * CCH + c) << 12);
  float* Rb = R + ((size_t)(s * CCH + c) << 12);
  for (int e = tid; e < 4096; e += 256)
    Rb[e] = (float)(accd[e] - (double)Yb[e]);
}

// ---------------------------------------------------------------------------
// HT = Xprev - Dt(R), f64, WITH fused level-1 histogram (top 11 abs-bits).
// Loop restructured: 11-row f64 register window per (c,j) -> 264 LDS reads
// (was 768). Per-block partial hist -> ph[lg][2048] (u16, no atomics).
// ---------------------------------------------------------------------------
__global__ __launch_bounds__(256) void convDt_k(const float* __restrict__ R,
    const double* __restrict__ Wt2d, const float* __restrict__ Xprev,
    float* __restrict__ HT, unsigned short* __restrict__ ph) {
  __shared__ float Rl[3][23][72];
  __shared__ unsigned hh[2048];
  int p = blockIdx.x;
  int lg = (p & 7) * 256 + (p >> 3);
  int b = lg >> 6; int rem = lg & 63; int ag = rem >> 2; int by = rem & 3;
  int row0 = by * 16;
  int tid = threadIdx.x;
  for (int e = tid; e < 2048; e += 256) hh[e] = 0;
  for (int e = tid; e < 3 * 23 * 72; e += 256) {
    int c = e / (23 * 72); int r2 = e - c * (23 * 72);
    int rr = r2 / 72; int cc = r2 - rr * 72;
    int gr = row0 + rr;
    float v = 0.0f;
    if (cc < OWW && gr < OHH)
      v = R[((size_t)(b * CCH + c) << 12) + (gr << 6) + cc];
    Rl[c][rr][cc] = v;
  }
  __syncthreads();
  int x = tid & 63, yg = tid >> 6;
  int yb = yg * 4;
  int a0 = ag * 8;
  double acc[8][4];
#pragma unroll
  for (int aa = 0; aa < 8; ++aa)
#pragma unroll
    for (int ty = 0; ty < 4; ++ty) acc[aa][ty] = 0.0;

  for (int c = 0; c < 3; ++c) {
#pragma unroll
    for (int j = 0; j < 8; ++j) {
      double rw[11];
#pragma unroll
      for (int r = 0; r < 11; ++r) rw[r] = (double)Rl[c][yb + r][x + j];
#pragma unroll
      for (int i = 0; i < 8; ++i) {
        const double* wp = Wt2d + ((c * 8 + i) * 8 + j) * 128 + a0;
#pragma unroll
        for (int aa = 0; aa < 8; ++aa) {
          double w = wp[aa];
          acc[aa][0] = fma(rw[i + 0], w, acc[aa][0]);
          acc[aa][1] = fma(rw[i + 1], w, acc[aa][1]);
          acc[aa][2] = fma(rw[i + 2], w, acc[aa][2]);
          acc[aa][3] = fma(rw[i + 3], w, acc[aa][3]);
        }
      }
    }
  }
  if (x < XW) {
    int gy0 = row0 + yb;
#pragma unroll
    for (int ty = 0; ty < 4; ++ty) {
      int yy = gy0 + ty;
      if (yy < XH) {
#pragma unroll
        for (int aa = 0; aa < 8; ++aa) {
          size_t xo = (size_t)(b * ATOMS + a0 + aa) * PIX + yy * XW + x;
          float fv = (float)((double)Xprev[xo] - acc[aa][ty]);
          HT[xo] = fv;
          unsigned u = __float_as_uint(fv) & 0x7fffffffu;
          atomicAdd(&hh[u >> 20], 1u);
        }
      }
    }
  }
  __syncthreads();
  unsigned short* php = ph + (size_t)lg * 2048;
  for (int e = tid; e < 2048; e += 256) php[e] = (unsigned short)hh[e];
}

// ---------------------------------------------------------------------------
// Level-1 rank find: reduce 64 partial hists per sample, locate bin of rank K.
// ---------------------------------------------------------------------------
__global__ __launch_bounds__(256) void find1_k(const unsigned short* __restrict__ ph,
    int* __restrict__ Bout, int* __restrict__ Kout) {
  int s = blockIdx.x;
  __shared__ unsigned hsum[2048];
  __shared__ unsigned part[256];
  int t = threadIdx.x;
  const unsigned short* pb = ph + (size_t)s * 64 * 2048;
  for (int bin = t; bin < 2048; bin += 256) {
    unsigned a = 0;
    for (int q = 0; q < 64; ++q) a += pb[(size_t)q * 2048 + bin];
    hsum[bin] = a;
  }
  __syncthreads();
  unsigned sum = 0;
#pragma unroll
  for (int e = 0; e < 8; ++e) sum += hsum[t * 8 + e];
  part[t] = sum;
  __syncthreads();
  if (t == 0) {
    int Kv = KSEL;
    unsigned cumBefore = 0;
    int bsel = 0;
    for (int q = 255; q >= 0; --q) {
      unsigned ps = part[q];
      if ((int)(cumBefore + ps) >= Kv) {
        for (int e = q * 8 + 7;; --e) {
          unsigned c2 = cumBefore + hsum[e];
          if ((int)c2 >= Kv) { bsel = e; break; }
          cumBefore = c2;
        }
        break;
      }
      cumBefore += ps;
    }
    Bout[s] = bsel;
    Kout[s] = Kv - (int)cumBefore;
  }
}

// Level-2 rank find on g2 (1024 bins).
template <int NB>
__global__ __launch_bounds__(256) void find_k(const unsigned* __restrict__ gh,
    const int* __restrict__ Kin, int* __restrict__ Bout, int* __restrict__ Kout) {
  int s = blockIdx.x;
  const unsigned* h = gh + s * NB;
  __shared__ unsigned part[256];
  constexpr int C = NB / 256;
  int t = threadIdx.x;
  unsigned sum = 0;
#pragma unroll
  for (int e = 0; e < C; ++e) sum += h[t * C + e];
  part[t] = sum;
  __syncthreads();
  if (t == 0) {
    int Kv = Kin[s];
    unsigned cumBefore = 0;
    int bsel = 0;
    for (int q = 255; q >= 0; --q) {
      unsigned ps = part[q];
      if ((int)(cumBefore + ps) >= Kv) {
        for (int e = q * C + C - 1;; --e) {
          unsigned c2 = cumBefore + h[e];
          if ((int)c2 >= Kv) { bsel = e; break; }
          cumBefore = c2;
        }
        break;
      }
      cumBefore += ps;
    }
    Bout[s] = bsel;
    Kout[s] = Kv - (int)cumBefore;
  }
}

__global__ __launch_bounds__(256) void hist2_k(const float* __restrict__ HT,
    const int* __restrict__ b1, unsigned* __restrict__ g2,
    int* __restrict__ cand, int* __restrict__ candcnt) {
  __shared__ unsigned h[1024];
  for (int e = threadIdx.x; e < 1024; e += 256) h[e] = 0;
  __syncthreads();
  int s = blockIdx.x >> 5;
  int chunk = blockIdx.x & 31;
  unsigned pre = (unsigned)b1[s];
  const unsigned* U = (const unsigned*)(HT + (size_t)s * NPS);
  for (int i = chunk * 256 + threadIdx.x; i < NPS; i += 32 * 256) {
    unsigned u = U[i] & 0x7fffffffu;
    if ((u >> 20) == pre) {
      atomicAdd(&h[(u >> 10) & 1023], 1u);
      int pos = atomicAdd(&candcnt[s], 1);
      if (pos < CANDCAP) cand[s * CANDCAP + pos] = i;
    }
  }
  __syncthreads();
  for (int e = threadIdx.x; e < 1024; e += 256)
    if (h[e]) atomicAdd(&g2[s * 1024 + e], h[e]);
}

__global__ __launch_bounds__(256) void pass3_k(const float* __restrict__ HT,
    const int* __restrict__ cand, const int* __restrict__ candcnt,
    const int* __restrict__ b1, const int* __restrict__ b2,
    const int* __restrict__ k2, unsigned* __restrict__ tau_out,
    int* __restrict__ cutoff_out) {
  int s = blockIdx.x;
  __shared__ unsigned h[1024];
  __shared__ int eqidx[1024];
  __shared__ int eqn;
  __shared__ unsigned tau_sh;
  __shared__ int k3_sh;
  for (int e = threadIdx.x; e < 1024; e += 256) h[e] = 0;
  if (threadIdx.x == 0) eqn = 0;
  __syncthreads();
  int n = candcnt[s];
  if (n > CANDCAP) n = CANDCAP;
  unsigned pre21 = (((unsigned)b1[s]) << 10) | (unsigned)b2[s];
  const unsigned* U = (const unsigned*)(HT + (size_t)s * NPS);
  for (int t = threadIdx.x; t < n; t += 256) {
    int i = cand[s * CANDCAP + t];
    unsigned u = U[i] & 0x7fffffffu;
    if ((u >> 10) == pre21) atomicAdd(&h[u & 1023], 1u);
  }
  __syncthreads();
  if (threadIdx.x == 0) {
    int Kv = k2[s];
    unsigned cumBefore = 0;
    int b3 = 0;
    for (int e = 1023; e >= 0; --e) {
      unsigned c2 = cumBefore + h[e];
      if ((int)c2 >= Kv) { b3 = e; break; }
      cumBefore = c2;
    }
    tau_sh = (pre21 << 10) | (unsigned)b3;
    k3_sh = Kv - (int)cumBefore;
  }
  __syncthreads();
  unsigned tau = tau_sh;
  for (int t = threadIdx.x; t < n; t += 256) {
    int i = cand[s * CANDCAP + t];
    unsigned u = U[i] & 0x7fffffffu;
    if (u == tau) {
      int pos = atomicAdd(&eqn, 1);
      if (pos < 1024) eqidx[pos] = i;
    }
  }
  __syncthreads();
  if (threadIdx.x == 0) {
    int m = eqn < 1024 ? eqn : 1024;
    int k3 = k3_sh;
    int cutoff;
    if (k3 >= m) {
      cutoff = 0x7fffffff;
    } else {
      int last = -1;
      for (int r = 0; r < k3; ++r) {
        int mn = 0x7fffffff;
        for (int q = 0; q < m; ++q) {
          int v = eqidx[q];
          if (v > last && v < mn) mn = v;
        }
        last = mn;
      }
      cutoff = last;
    }
    tau_out[s] = tau;
    cutoff_out[s] = cutoff;
  }
}

// ---------------------------------------------------------------------------
// Threshold write + nz-list emit with per-block aggregation.
// Block = (sample, 1/128 segment of NPS = 3249 els). One global atomic/block.
// ---------------------------------------------------------------------------
__global__ __launch_bounds__(256) void write_k(const float* __restrict__ HT,
    const unsigned* __restrict__ tau, const int* __restrict__ cutoff,
    float* __restrict__ Xo, int* __restrict__ nzidx, float* __restrict__ nzval,
    int* __restrict__ nzcnt) {
  __shared__ int lidx[2048];
  __shared__ float lval[2048];
  __shared__ int lcnt, lbase;
  int s = blockIdx.x >> 7;
  int seg = blockIdx.x & 127;
  int tid = threadIdx.x;
  if (tid == 0) lcnt = 0;
  __syncthreads();
  unsigned tt = tau[s];
  int co = cutoff[s];
  size_t sbase = (size_t)s * NPS;
  int lo = seg * 3249;
  for (int ch = 0; ch < 13; ++ch) {
    int il = lo + ch * 256 + tid;
    if (il < lo + 3249) {
      float xv = HT[sbase + il];
      unsigned u = __float_as_uint(xv) & 0x7fffffffu;
      float o = 0.0f;
      if (u > tt || (u == tt && il <= co)) {
        o = xv;
        int pos = atomicAdd(&lcnt, 1);
        if (pos < 2048) { lidx[pos] = il; lval[pos] = xv; }
      }
      Xo[sbase + il] = o;
    }
  }
  __syncthreads();
  if (tid == 0) lbase = atomicAdd(&nzcnt[s], lcnt);
  __syncthreads();
  int n = lcnt < 2048 ? lcnt : 2048;
  int base = lbase;
  for (int e = tid; e < n; e += 256) {
    int g = base + e;
    if (g < KSEL) { nzidx[s * KSEL + g] = lidx[e]; nzval[s * KSEL + g] = lval[e]; }
  }
}

extern "C" void kernel_launch(void* const* d_in, const int* in_sizes, int n_in,
                              void* d_out, int out_size, void* d_ws, size_t ws_size,
                              hipStream_t stream) {
  const float* Y  = (const float*)d_in[0];
  const float* X0 = (const float*)d_in[1];
  const float* Wg = (const float*)d_in[2];
  float* Xout = (float*)d_out;

  double* WDd  = (double*)d_ws;                        // NW doubles
  double* Wt2d = WDd + NW;                             // NW doubles
  float* HT   = (float*)(Wt2d + NW);                   // NTOT floats
  float* Rbuf = HT + NTOT;                             // RTOT floats
  unsigned short* ph = (unsigned short*)(Rbuf + RTOT); // 2048*2048 u16
  unsigned* g2 = (unsigned*)(ph + 2048 * 2048);        // 32*1024
  int* candcnt = (int*)(g2 + 32 * 1024);               // 32
  int* nzcnt = candcnt + 32;                           // 32
  int* b1 = nzcnt + 32;
  int* k1 = b1 + 32;
  int* b2 = k1 + 32;
  int* k2 = b2 + 32;
  unsigned* tau = (unsigned*)(k2 + 32);
  int* cutoff = (int*)(tau + 32);
  int* cand = cutoff + 32;                             // 32*CANDCAP
  int* nzidx = cand + 32 * CANDCAP;                    // 32*KSEL
  float* nzval = (float*)(nzidx + 32 * KSEL);          // 32*KSEL
  size_t zero_bytes = (size_t)(32 * 1024 + 32 + 32) * 4;  // g2, candcnt, nzcnt

  wprep_k<<<dim3((NW + 255) / 256), dim3(256), 0, stream>>>(Wg, WDd, Wt2d);

  for (int it = 0; it < 3; ++it) {
    const float* Xsrc = (it == 0) ? X0 : (const float*)Xout;
    hipMemsetAsync(g2, 0, zero_bytes, stream);
    if (it == 0) {
      convD_k<<<dim3(512), dim3(256), 0, stream>>>(Xsrc, WDd, Y, Rbuf);
    } else {
      convD_sparse_k<<<dim3(BATCH * CCH), dim3(256), 0, stream>>>(
          Wg, nzidx, nzval, Y, Rbuf);
    }
    convDt_k<<<dim3(2048), dim3(256), 0, stream>>>(Rbuf, Wt2d, Xsrc, HT, ph);
    find1_k<<<dim3(BATCH), dim3(256), 0, stream>>>(ph, b1, k1);
    hist2_k<<<dim3(BATCH * 32), dim3(256), 0, stream>>>(HT, b1, g2, cand, candcnt);
    find_k<1024><<<dim3(BATCH), dim3(256), 0, stream>>>(g2, k1, b2, k2);
    pass3_k<<<dim3(BATCH), dim3(256), 0, stream>>>(HT, cand, candcnt, b1, b2, k2, tau, cutoff);
    write_k<<<dim3(BATCH * 128), dim3(256), 0, stream>>>(HT, tau, cutoff, Xout,
                                                         nzidx, nzval, nzcnt);
  }
}

// Round 5
// 1740.081 us; speedup vs baseline: 3.6556x; 1.1193x over previous
//
#include <hip/hip_runtime.h>

#define BATCH 32
#define ATOMS 128
#define CCH 3
#define XH 57
#define XW 57
#define OHH 64
#define OWW 64
#define KSEL 2000
#define PIX (XH*XW)            // 3249
#define NPS (ATOMS*PIX)        // 415872 per-sample X elements
#define NTOT (BATCH*NPS)       // 13307904
#define RPS (CCH*OHH*OWW)      // 12288 per-sample R elements
#define RTOT (BATCH*RPS)       // 393216
#define CANDCAP 32768
#define NW 24576               // weight elements 128*3*8*8
#define WSEG 102               // write_k segments of 1024 float4 per sample

// ---------------------------------------------------------------------------
// Weight prep (once): WDd[a][kh][c][kw] f64 for dense convD.
// ---------------------------------------------------------------------------
__global__ __launch_bounds__(256) void wprep_k(const float* __restrict__ Wg,
    double* __restrict__ WDd) {
  int e = blockIdx.x * 256 + threadIdx.x;
  if (e >= NW) return;
  int kw = e & 7; int t = e >> 3; int c = t % 3; t /= 3; int kh = t & 7; int a = t >> 3;
  WDd[e] = (double)Wg[(a*3 + c)*64 + kh*8 + kw];
}

// Rd = -Y (f64), dense-path init.
__global__ __launch_bounds__(256) void rinit_k(const float* __restrict__ Y,
    double* __restrict__ Rd) {
  int i = blockIdx.x * 256 + threadIdx.x;
  if (i < RTOT) Rd[i] = -(double)Y[i];
}

// R = (float)Rd, dense-path finish.
__global__ __launch_bounds__(256) void rfin_k(const double* __restrict__ Rd,
    float* __restrict__ R) {
  int i = blockIdx.x * 256 + threadIdx.x;
  if (i < RTOT) R[i] = (float)Rd[i];
}

// ---------------------------------------------------------------------------
// DENSE R += D(X) (iteration 0 only). Block = (b, 4-row band, atom-half).
// 4 waves x 16 atoms each (2 per 8-atom LDS chunk); lane = ox.
// Per-thread f64 accumulators -> direct global f64 atomics into Rd.
// grid = 1024 (XCD-swizzled). LDS 25.3KB -> 4 blocks/CU resident.
// ---------------------------------------------------------------------------
__global__ __launch_bounds__(256) void convD_k(const float* __restrict__ X,
    const double* __restrict__ WDd, double* __restrict__ Rd) {
  __shared__ float Xs[8][11][72];
  int p = blockIdx.x;
  int lg = (p & 7) * 128 + (p >> 3);          // bijective: 1024 = 8*128
  int b = lg >> 5; int rem = lg & 31; int band = rem >> 1; int half = rem & 1;
  int row0 = band * 4;
  int a_base = half * 64;
  int tid = threadIdx.x;
  int ox = tid & 63;
  int wv = __builtin_amdgcn_readfirstlane(tid >> 6);
  const float* Xb = X + (size_t)b * NPS;

  double acc[4][3];
#pragma unroll
  for (int ty = 0; ty < 4; ++ty)
#pragma unroll
    for (int c = 0; c < 3; ++c) acc[ty][c] = 0.0;

  for (int ch = 0; ch < 8; ++ch) {
    __syncthreads();
    for (int e = tid; e < 8 * 11 * 72; e += 256) {
      int ai = e / 792; int rem2 = e - ai * 792;
      int r = rem2 / 72; int ss = rem2 - r * 72;
      int gy = row0 - 7 + r;
      int xcol = ss - 7;
      int a = a_base + ch * 8 + ai;
      float v = 0.0f;
      if ((unsigned)xcol < (unsigned)XW && (unsigned)gy < (unsigned)XH)
        v = Xb[a * PIX + gy * XW + xcol];
      Xs[ai][r][ss] = v;
    }
    __syncthreads();
#pragma unroll
    for (int j = 0; j < 2; ++j) {
      int ai = (wv << 1) + j;
      int a  = a_base + ch * 8 + ai;
      const double* Wa = WDd + a * 192;       // [kh][c][kw]
#pragma unroll
      for (int r = 0; r < 11; ++r) {
        int gy = row0 - 7 + r;
        if ((unsigned)gy >= (unsigned)XH) continue;   // uniform
        double xd[8];
#pragma unroll
        for (int t = 0; t < 8; ++t) xd[t] = (double)Xs[ai][r][ox + t];
#pragma unroll
        for (int ty = 0; ty < 4; ++ty) {
          int kh = ty + 7 - r;
          if ((unsigned)kh < 8u) {
            const double* Wk = Wa + kh * 24;
#pragma unroll
            for (int kw = 0; kw < 8; ++kw) {
              acc[ty][0] = fma(xd[7 - kw], Wk[kw],      acc[ty][0]);
              acc[ty][1] = fma(xd[7 - kw], Wk[8 + kw],  acc[ty][1]);
              acc[ty][2] = fma(xd[7 - kw], Wk[16 + kw], acc[ty][2]);
            }
          }
        }
      }
    }
  }
#pragma unroll
  for (int ty = 0; ty < 4; ++ty) {
    int oy = row0 + ty;
#pragma unroll
    for (int c = 0; c < 3; ++c)
      atomicAdd(&Rd[((size_t)(b * CCH + c) << 12) + (oy << 6) + ox], acc[ty][c]);
  }
}

// ---------------------------------------------------------------------------
// SPARSE R = D(X) - Y (iterations 1,2). Block = (sample, c, 8-row band).
// Scans nz list with +/-7 row filter; LDS f64 tile [8][64] (4KB) via ds
// atomics; f32 weights (exact cvt) 32KB; direct R store, no global atomics.
// grid = 768 (swizzled), 3 blocks/CU.
// ---------------------------------------------------------------------------
__global__ __launch_bounds__(256) void convD_sparse_k(const float* __restrict__ Wg,
    const int* __restrict__ nzidx, const float* __restrict__ nzval,
    const float* __restrict__ Y, float* __restrict__ R) {
  __shared__ double accd[512];       // [rr][ox]
  __shared__ float Wf[8192];         // [a][kh][kw] for this c
  __shared__ int   li[KSEL];
  __shared__ float lv[KSEL];
  int p = blockIdx.x;
  int lg = (p & 7) * 96 + (p >> 3);  // bijective: 768 = 8*96
  int s = lg / 24; int r = lg % 24; int c = r >> 3; int band = r & 7;
  int row0 = band * 8;
  int tid = threadIdx.x;
  for (int e = tid; e < 512; e += 256) accd[e] = 0.0;
  for (int e = tid; e < 8192; e += 256) {
    int a = e >> 6, k2 = e & 63;
    Wf[e] = Wg[(a * 3 + c) * 64 + k2];
  }
  for (int e = tid; e < KSEL; e += 256) {
    li[e] = nzidx[s * KSEL + e];
    lv[e] = nzval[s * KSEL + e];
  }
  __syncthreads();
  int slot = tid >> 3, kw = tid & 7;
  for (int e = slot; e < KSEL; e += 32) {
    int idx = li[e];
    int a = (int)((unsigned)idx / 3249u);
    int pp = idx - a * 3249;
    int y = (int)((unsigned)pp / 57u);
    int x = pp - y * 57;
    int dy = y - row0;
    if (dy < -7 || dy > 7) continue;
    double val = (double)lv[e];
    const float* wp = Wf + (a << 6) + kw;
#pragma unroll
    for (int kh = 0; kh < 8; ++kh) {
      int rr = dy + kh;
      if ((unsigned)rr < 8u)
        __hip_atomic_fetch_add(&accd[(rr << 6) + x + kw],
                               val * (double)wp[kh << 3],
                               __ATOMIC_RELAXED, __HIP_MEMORY_SCOPE_WORKGROUP);
    }
  }
  __syncthreads();
  const float* Yb = Y + (((size_t)(s * CCH + c)) << 12) + (row0 << 6);
  float* Rb = R + (((size_t)(s * CCH + c)) << 12) + (row0 << 6);
  for (int e = tid; e < 512; e += 256)
    Rb[e] = (float)(accd[e] - (double)Yb[e]);
}

// ---------------------------------------------------------------------------
// HT = Xprev - Dt(R), f64, fused level-1 histogram -> g1 (global atomics).
// Weights for the block's 8 atoms staged in LDS as f32 (exact on cvt).
// grid = 2048 (swizzled). LDS 34KB.
// ---------------------------------------------------------------------------
__global__ __launch_bounds__(256) void convDt_k(const float* __restrict__ R,
    const float* __restrict__ Wg, const float* __restrict__ Xprev,
    float* __restrict__ HT, unsigned* __restrict__ g1) {
  __shared__ float Rl[3][23][72];
  __shared__ float Wl[1536];         // [c][i][j][aa]
  __shared__ unsigned hh[2048];
  int p = blockIdx.x;
  int lg = (p & 7) * 256 + (p >> 3);
  int b = lg >> 6; int rem = lg & 63; int ag = rem >> 2; int by = rem & 3;
  int row0 = by * 16;
  int a0 = ag * 8;
  int tid = threadIdx.x;
  for (int e = tid; e < 2048; e += 256) hh[e] = 0;
  for (int e = tid; e < 1536; e += 256) {
    int aa = e & 7; int j = (e >> 3) & 7; int i = (e >> 6) & 7; int c = e >> 9;
    // Wt[a][c][j][i] = W_D[a][c][j][i] spatially transposed use: W[a][c][j*8+i]
    Wl[e] = Wg[((a0 + aa) * 3 + c) * 64 + j * 8 + i];
  }
  for (int e = tid; e < 3 * 23 * 72; e += 256) {
    int c = e / (23 * 72); int r2 = e - c * (23 * 72);
    int rr = r2 / 72; int cc = r2 - rr * 72;
    int gr = row0 + rr;
    float v = 0.0f;
    if (cc < OWW && gr < OHH)
      v = R[((size_t)(b * CCH + c) << 12) + (gr << 6) + cc];
    Rl[c][rr][cc] = v;
  }
  __syncthreads();
  int x = tid & 63, yg = tid >> 6;
  int yb = yg * 4;
  double acc[8][4];
#pragma unroll
  for (int aa = 0; aa < 8; ++aa)
#pragma unroll
    for (int ty = 0; ty < 4; ++ty) acc[aa][ty] = 0.0;

  for (int c = 0; c < 3; ++c) {
#pragma unroll
    for (int j = 0; j < 8; ++j) {
      double rw[11];
#pragma unroll
      for (int r = 0; r < 11; ++r) rw[r] = (double)Rl[c][yb + r][x + j];
#pragma unroll
      for (int i = 0; i < 8; ++i) {
        const float* wp = &Wl[((c * 8 + i) * 8 + j) * 8];
#pragma unroll
        for (int aa = 0; aa < 8; ++aa) {
          double w = (double)wp[aa];
          acc[aa][0] = fma(rw[i + 0], w, acc[aa][0]);
          acc[aa][1] = fma(rw[i + 1], w, acc[aa][1]);
          acc[aa][2] = fma(rw[i + 2], w, acc[aa][2]);
          acc[aa][3] = fma(rw[i + 3], w, acc[aa][3]);
        }
      }
    }
  }
  if (x < XW) {
    int gy0 = row0 + yb;
#pragma unroll
    for (int ty = 0; ty < 4; ++ty) {
      int yy = gy0 + ty;
      if (yy < XH) {
#pragma unroll
        for (int aa = 0; aa < 8; ++aa) {
          size_t xo = (size_t)(b * ATOMS + a0 + aa) * PIX + yy * XW + x;
          float fv = (float)((double)Xprev[xo] - acc[aa][ty]);
          HT[xo] = fv;
          unsigned u = __float_as_uint(fv) & 0x7fffffffu;
          atomicAdd(&hh[u >> 20], 1u);
        }
      }
    }
  }
  __syncthreads();
  unsigned* gp = g1 + (size_t)b * 2048;
  for (int e = tid; e < 2048; e += 256)
    if (hh[e]) atomicAdd(&gp[e], hh[e]);
}

// Find bin containing rank Kv (descending); Kin==nullptr -> KSEL.
template <int NB>
__global__ __launch_bounds__(256) void find_k(const unsigned* __restrict__ gh,
    const int* __restrict__ Kin, int* __restrict__ Bout, int* __restrict__ Kout) {
  int s = blockIdx.x;
  const unsigned* h = gh + s * NB;
  __shared__ unsigned part[256];
  constexpr int C = NB / 256;
  int t = threadIdx.x;
  unsigned sum = 0;
#pragma unroll
  for (int e = 0; e < C; ++e) sum += h[t * C + e];
  part[t] = sum;
  __syncthreads();
  if (t == 0) {
    int Kv = Kin ? Kin[s] : KSEL;
    unsigned cumBefore = 0;
    int bsel = 0;
    for (int q = 255; q >= 0; --q) {
      unsigned ps = part[q];
      if ((int)(cumBefore + ps) >= Kv) {
        for (int e = q * C + C - 1;; --e) {
          unsigned c2 = cumBefore + h[e];
          if ((int)c2 >= Kv) { bsel = e; break; }
          cumBefore = c2;
        }
        break;
      }
      cumBefore += ps;
    }
    Bout[s] = bsel;
    Kout[s] = Kv - (int)cumBefore;
  }
}

// Level 2: float4 scan; histogram next 10 bits within bin b1 + gather cands.
__global__ __launch_bounds__(256) void hist2_k(const float* __restrict__ HT,
    const int* __restrict__ b1, unsigned* __restrict__ g2,
    int* __restrict__ cand, int* __restrict__ candcnt) {
  __shared__ unsigned h[1024];
  for (int e = threadIdx.x; e < 1024; e += 256) h[e] = 0;
  __syncthreads();
  int s = blockIdx.x >> 5;
  int chunk = blockIdx.x & 31;
  unsigned pre = (unsigned)b1[s];
  const uint4* U4 = (const uint4*)(HT + (size_t)s * NPS);
  for (int i4 = chunk * 256 + threadIdx.x; i4 < NPS / 4; i4 += 32 * 256) {
    uint4 v = U4[i4];
    unsigned uu[4] = {v.x, v.y, v.z, v.w};
#pragma unroll
    for (int t = 0; t < 4; ++t) {
      unsigned u = uu[t] & 0x7fffffffu;
      if ((u >> 20) == pre) {
        atomicAdd(&h[(u >> 10) & 1023], 1u);
        int pos = atomicAdd(&candcnt[s], 1);
        if (pos < CANDCAP) cand[s * CANDCAP + pos] = i4 * 4 + t;
      }
    }
  }
  __syncthreads();
  for (int e = threadIdx.x; e < 1024; e += 256)
    if (h[e]) atomicAdd(&g2[s * 1024 + e], h[e]);
}

// Level 3 + tie resolution over candidate list (one block per sample).
__global__ __launch_bounds__(256) void pass3_k(const float* __restrict__ HT,
    const int* __restrict__ cand, const int* __restrict__ candcnt,
    const int* __restrict__ b1, const int* __restrict__ b2,
    const int* __restrict__ k2, unsigned* __restrict__ tau_out,
    int* __restrict__ cutoff_out) {
  int s = blockIdx.x;
  __shared__ unsigned h[1024];
  __shared__ int eqidx[1024];
  __shared__ int eqn;
  __shared__ unsigned tau_sh;
  __shared__ int k3_sh;
  for (int e = threadIdx.x; e < 1024; e += 256) h[e] = 0;
  if (threadIdx.x == 0) eqn = 0;
  __syncthreads();
  int n = candcnt[s];
  if (n > CANDCAP) n = CANDCAP;
  unsigned pre21 = (((unsigned)b1[s]) << 10) | (unsigned)b2[s];
  const unsigned* U = (const unsigned*)(HT + (size_t)s * NPS);
  for (int t = threadIdx.x; t < n; t += 256) {
    int i = cand[s * CANDCAP + t];
    unsigned u = U[i] & 0x7fffffffu;
    if ((u >> 10) == pre21) atomicAdd(&h[u & 1023], 1u);
  }
  __syncthreads();
  if (threadIdx.x == 0) {
    int Kv = k2[s];
    unsigned cumBefore = 0;
    int b3 = 0;
    for (int e = 1023; e >= 0; --e) {
      unsigned c2 = cumBefore + h[e];
      if ((int)c2 >= Kv) { b3 = e; break; }
      cumBefore = c2;
    }
    tau_sh = (pre21 << 10) | (unsigned)b3;
    k3_sh = Kv - (int)cumBefore;
  }
  __syncthreads();
  unsigned tau = tau_sh;
  for (int t = threadIdx.x; t < n; t += 256) {
    int i = cand[s * CANDCAP + t];
    unsigned u = U[i] & 0x7fffffffu;
    if (u == tau) {
      int pos = atomicAdd(&eqn, 1);
      if (pos < 1024) eqidx[pos] = i;
    }
  }
  __syncthreads();
  if (threadIdx.x == 0) {
    int m = eqn < 1024 ? eqn : 1024;
    int k3 = k3_sh;
    int cutoff;
    if (k3 >= m) {
      cutoff = 0x7fffffff;
    } else {
      int last = -1;
      for (int r = 0; r < k3; ++r) {
        int mn = 0x7fffffff;
        for (int q = 0; q < m; ++q) {
          int v = eqidx[q];
          if (v > last && v < mn) mn = v;
        }
        last = mn;
      }
      cutoff = last;
    }
    tau_out[s] = tau;
    cutoff_out[s] = cutoff;
  }
}

// ---------------------------------------------------------------------------
// Threshold write (float4) + nz-list emit, per-block LDS aggregation.
// Block = (sample, 1024-float4 segment). One global atomic per block.
// ---------------------------------------------------------------------------
__global__ __launch_bounds__(256) void write_k(const float* __restrict__ HT,
    const unsigned* __restrict__ tau, const int* __restrict__ cutoff,
    float* __restrict__ Xo, int* __restrict__ nzidx, float* __restrict__ nzval,
    int* __restrict__ nzcnt) {
  __shared__ int lidx[2048];
  __shared__ float lval[2048];
  __shared__ int lcnt, lbase;
  int s = blockIdx.x / WSEG;
  int seg = blockIdx.x % WSEG;
  int tid = threadIdx.x;
  if (tid == 0) lcnt = 0;
  __syncthreads();
  unsigned tt = tau[s];
  int co = cutoff[s];
  size_t sbase = (size_t)s * NPS;
  const float4* H4 = (const float4*)(HT + sbase);
  float4* X4 = (float4*)(Xo + sbase);
  int f0 = seg * 1024;
#pragma unroll
  for (int rr = 0; rr < 4; ++rr) {
    int i4 = f0 + rr * 256 + tid;
    if (i4 < NPS / 4) {
      float4 v = H4[i4];
      float vv[4] = {v.x, v.y, v.z, v.w};
      float oo[4];
#pragma unroll
      for (int t = 0; t < 4; ++t) {
        int il = i4 * 4 + t;
        unsigned u = __float_as_uint(vv[t]) & 0x7fffffffu;
        bool keep = (u > tt) || (u == tt && il <= co);
        oo[t] = keep ? vv[t] : 0.0f;
        if (keep) {
          int pos = atomicAdd(&lcnt, 1);
          if (pos < 2048) { lidx[pos] = il; lval[pos] = vv[t]; }
        }
      }
      X4[i4] = make_float4(oo[0], oo[1], oo[2], oo[3]);
    }
  }
  __syncthreads();
  if (tid == 0) lbase = atomicAdd(&nzcnt[s], lcnt);
  __syncthreads();
  int n = lcnt < 2048 ? lcnt : 2048;
  int base = lbase;
  for (int e = tid; e < n; e += 256) {
    int g = base + e;
    if (g < KSEL) { nzidx[s * KSEL + g] = lidx[e]; nzval[s * KSEL + g] = lval[e]; }
  }
}

extern "C" void kernel_launch(void* const* d_in, const int* in_sizes, int n_in,
                              void* d_out, int out_size, void* d_ws, size_t ws_size,
                              hipStream_t stream) {
  const float* Y  = (const float*)d_in[0];
  const float* X0 = (const float*)d_in[1];
  const float* Wg = (const float*)d_in[2];
  float* Xout = (float*)d_out;

  double* WDd  = (double*)d_ws;                        // NW f64
  float* HT   = (float*)(WDd + NW);                    // NTOT f32
  float* Rbuf = HT + NTOT;                             // RTOT f32
  double* Rd  = (double*)(Rbuf + RTOT);                // RTOT f64
  unsigned* g1 = (unsigned*)(Rd + RTOT);               // 32*2048
  unsigned* g2 = g1 + 32 * 2048;                       // 32*1024
  int* candcnt = (int*)(g2 + 32 * 1024);               // 32
  int* nzcnt = candcnt + 32;                           // 32
  int* b1 = nzcnt + 32;
  int* k1 = b1 + 32;
  int* b2 = k1 + 32;
  int* k2 = b2 + 32;
  unsigned* tau = (unsigned*)(k2 + 32);
  int* cutoff = (int*)(tau + 32);
  int* cand = cutoff + 32;                             // 32*CANDCAP
  int* nzidx = cand + 32 * CANDCAP;                    // 32*KSEL
  float* nzval = (float*)(nzidx + 32 * KSEL);          // 32*KSEL
  size_t zero_bytes = (size_t)(32 * 2048 + 32 * 1024 + 32 + 32) * 4;

  wprep_k<<<dim3((NW + 255) / 256), dim3(256), 0, stream>>>(Wg, WDd);

  for (int it = 0; it < 3; ++it) {
    const float* Xsrc = (it == 0) ? X0 : (const float*)Xout;
    hipMemsetAsync(g1, 0, zero_bytes, stream);  // g1, g2, candcnt, nzcnt
    if (it == 0) {
      rinit_k<<<dim3((RTOT + 255) / 256), dim3(256), 0, stream>>>(Y, Rd);
      convD_k<<<dim3(1024), dim3(256), 0, stream>>>(Xsrc, WDd, Rd);
      rfin_k<<<dim3((RTOT + 255) / 256), dim3(256), 0, stream>>>(Rd, Rbuf);
    } else {
      convD_sparse_k<<<dim3(BATCH * CCH * 8), dim3(256), 0, stream>>>(
          Wg, nzidx, nzval, Y, Rbuf);
    }
    convDt_k<<<dim3(2048), dim3(256), 0, stream>>>(Rbuf, Wg, Xsrc, HT, g1);
    find_k<2048><<<dim3(BATCH), dim3(256), 0, stream>>>(g1, (const int*)nullptr, b1, k1);
    hist2_k<<<dim3(BATCH * 32), dim3(256), 0, stream>>>(HT, b1, g2, cand, candcnt);
    find_k<1024><<<dim3(BATCH), dim3(256), 0, stream>>>(g2, k1, b2, k2);
    pass3_k<<<dim3(BATCH), dim3(256), 0, stream>>>(HT, cand, candcnt, b1, b2, k2, tau, cutoff);
    write_k<<<dim3(BATCH * WSEG), dim3(256), 0, stream>>>(HT, tau, cutoff, Xout,
                                                          nzidx, nzval, nzcnt);
  }
}

// Round 6
// 1176.555 us; speedup vs baseline: 5.4065x; 1.4790x over previous
//
#include <hip/hip_runtime.h>

#define BATCH 32
#define ATOMS 128
#define CCH 3
#define XH 57
#define XW 57
#define OHH 64
#define OWW 64
#define KSEL 2000
#define PIX (XH*XW)            // 3249
#define NPS (ATOMS*PIX)        // 415872 per-sample X elements
#define NTOT (BATCH*NPS)       // 13307904
#define RPS (CCH*OHH*OWW)      // 12288 per-sample R elements
#define RTOT (BATCH*RPS)       // 393216
#define CANDCAP 32768
#define NW 24576               // weight elements 128*3*8*8
#define WSEG 102               // write_k segments of 1024 float4 per sample

// ---------------------------------------------------------------------------
// Weight prep (once): WDd[a][kh][c][kw] f64 for dense convD.
// ---------------------------------------------------------------------------
__global__ __launch_bounds__(256) void wprep_k(const float* __restrict__ Wg,
    double* __restrict__ WDd) {
  int e = blockIdx.x * 256 + threadIdx.x;
  if (e >= NW) return;
  int kw = e & 7; int t = e >> 3; int c = t % 3; t /= 3; int kh = t & 7; int a = t >> 3;
  WDd[e] = (double)Wg[(a*3 + c)*64 + kh*8 + kw];
}

// Rd = -Y (f64), dense-path init.
__global__ __launch_bounds__(256) void rinit_k(const float* __restrict__ Y,
    double* __restrict__ Rd) {
  int i = blockIdx.x * 256 + threadIdx.x;
  if (i < RTOT) Rd[i] = -(double)Y[i];
}

// R = (float)Rd, dense-path finish.
__global__ __launch_bounds__(256) void rfin_k(const double* __restrict__ Rd,
    float* __restrict__ R) {
  int i = blockIdx.x * 256 + threadIdx.x;
  if (i < RTOT) R[i] = (float)Rd[i];
}

// ---------------------------------------------------------------------------
// DENSE R += D(X) (iteration 0 only). Unchanged from round 5.
// ---------------------------------------------------------------------------
__global__ __launch_bounds__(256) void convD_k(const float* __restrict__ X,
    const double* __restrict__ WDd, double* __restrict__ Rd) {
  __shared__ float Xs[8][11][72];
  int p = blockIdx.x;
  int lg = (p & 7) * 128 + (p >> 3);          // bijective: 1024 = 8*128
  int b = lg >> 5; int rem = lg & 31; int band = rem >> 1; int half = rem & 1;
  int row0 = band * 4;
  int a_base = half * 64;
  int tid = threadIdx.x;
  int ox = tid & 63;
  int wv = __builtin_amdgcn_readfirstlane(tid >> 6);
  const float* Xb = X + (size_t)b * NPS;

  double acc[4][3];
#pragma unroll
  for (int ty = 0; ty < 4; ++ty)
#pragma unroll
    for (int c = 0; c < 3; ++c) acc[ty][c] = 0.0;

  for (int ch = 0; ch < 8; ++ch) {
    __syncthreads();
    for (int e = tid; e < 8 * 11 * 72; e += 256) {
      int ai = e / 792; int rem2 = e - ai * 792;
      int r = rem2 / 72; int ss = rem2 - r * 72;
      int gy = row0 - 7 + r;
      int xcol = ss - 7;
      int a = a_base + ch * 8 + ai;
      float v = 0.0f;
      if ((unsigned)xcol < (unsigned)XW && (unsigned)gy < (unsigned)XH)
        v = Xb[a * PIX + gy * XW + xcol];
      Xs[ai][r][ss] = v;
    }
    __syncthreads();
#pragma unroll
    for (int j = 0; j < 2; ++j) {
      int ai = (wv << 1) + j;
      int a  = a_base + ch * 8 + ai;
      const double* Wa = WDd + a * 192;       // [kh][c][kw]
#pragma unroll
      for (int r = 0; r < 11; ++r) {
        int gy = row0 - 7 + r;
        if ((unsigned)gy >= (unsigned)XH) continue;   // uniform
        double xd[8];
#pragma unroll
        for (int t = 0; t < 8; ++t) xd[t] = (double)Xs[ai][r][ox + t];
#pragma unroll
        for (int ty = 0; ty < 4; ++ty) {
          int kh = ty + 7 - r;
          if ((unsigned)kh < 8u) {
            const double* Wk = Wa + kh * 24;
#pragma unroll
            for (int kw = 0; kw < 8; ++kw) {
              acc[ty][0] = fma(xd[7 - kw], Wk[kw],      acc[ty][0]);
              acc[ty][1] = fma(xd[7 - kw], Wk[8 + kw],  acc[ty][1]);
              acc[ty][2] = fma(xd[7 - kw], Wk[16 + kw], acc[ty][2]);
            }
          }
        }
      }
    }
  }
#pragma unroll
  for (int ty = 0; ty < 4; ++ty) {
    int oy = row0 + ty;
#pragma unroll
    for (int c = 0; c < 3; ++c)
      atomicAdd(&Rd[((size_t)(b * CCH + c) << 12) + (oy << 6) + ox], acc[ty][c]);
  }
}

// ---------------------------------------------------------------------------
// SPARSE R = D(X) - Y (iterations 1,2). Unchanged from round 5.
// ---------------------------------------------------------------------------
__global__ __launch_bounds__(256) void convD_sparse_k(const float* __restrict__ Wg,
    const int* __restrict__ nzidx, const float* __restrict__ nzval,
    const float* __restrict__ Y, float* __restrict__ R) {
  __shared__ double accd[512];       // [rr][ox]
  __shared__ float Wf[8192];         // [a][kh][kw] for this c
  __shared__ int   li[KSEL];
  __shared__ float lv[KSEL];
  int p = blockIdx.x;
  int lg = (p & 7) * 96 + (p >> 3);  // bijective: 768 = 8*96
  int s = lg / 24; int r = lg % 24; int c = r >> 3; int band = r & 7;
  int row0 = band * 8;
  int tid = threadIdx.x;
  for (int e = tid; e < 512; e += 256) accd[e] = 0.0;
  for (int e = tid; e < 8192; e += 256) {
    int a = e >> 6, k2 = e & 63;
    Wf[e] = Wg[(a * 3 + c) * 64 + k2];
  }
  for (int e = tid; e < KSEL; e += 256) {
    li[e] = nzidx[s * KSEL + e];
    lv[e] = nzval[s * KSEL + e];
  }
  __syncthreads();
  int slot = tid >> 3, kw = tid & 7;
  for (int e = slot; e < KSEL; e += 32) {
    int idx = li[e];
    int a = (int)((unsigned)idx / 3249u);
    int pp = idx - a * 3249;
    int y = (int)((unsigned)pp / 57u);
    int x = pp - y * 57;
    int dy = y - row0;
    if (dy < -7 || dy > 7) continue;
    double val = (double)lv[e];
    const float* wp = Wf + (a << 6) + kw;
#pragma unroll
    for (int kh = 0; kh < 8; ++kh) {
      int rr = dy + kh;
      if ((unsigned)rr < 8u)
        __hip_atomic_fetch_add(&accd[(rr << 6) + x + kw],
                               val * (double)wp[kh << 3],
                               __ATOMIC_RELAXED, __HIP_MEMORY_SCOPE_WORKGROUP);
    }
  }
  __syncthreads();
  const float* Yb = Y + (((size_t)(s * CCH + c)) << 12) + (row0 << 6);
  float* Rb = R + (((size_t)(s * CCH + c)) << 12) + (row0 << 6);
  for (int e = tid; e < 512; e += 256)
    Rb[e] = (float)(accd[e] - (double)Yb[e]);
}

// ---------------------------------------------------------------------------
// HT = Xprev - Dt(R), f64, fused level-1 histogram -> g1 (global atomics).
// Unchanged from round 5.
// ---------------------------------------------------------------------------
__global__ __launch_bounds__(256) void convDt_k(const float* __restrict__ R,
    const float* __restrict__ Wg, const float* __restrict__ Xprev,
    float* __restrict__ HT, unsigned* __restrict__ g1) {
  __shared__ float Rl[3][23][72];
  __shared__ float Wl[1536];         // [c][i][j][aa]
  __shared__ unsigned hh[2048];
  int p = blockIdx.x;
  int lg = (p & 7) * 256 + (p >> 3);
  int b = lg >> 6; int rem = lg & 63; int ag = rem >> 2; int by = rem & 3;
  int row0 = by * 16;
  int a0 = ag * 8;
  int tid = threadIdx.x;
  for (int e = tid; e < 2048; e += 256) hh[e] = 0;
  for (int e = tid; e < 1536; e += 256) {
    int aa = e & 7; int j = (e >> 3) & 7; int i = (e >> 6) & 7; int c = e >> 9;
    Wl[e] = Wg[((a0 + aa) * 3 + c) * 64 + j * 8 + i];
  }
  for (int e = tid; e < 3 * 23 * 72; e += 256) {
    int c = e / (23 * 72); int r2 = e - c * (23 * 72);
    int rr = r2 / 72; int cc = r2 - rr * 72;
    int gr = row0 + rr;
    float v = 0.0f;
    if (cc < OWW && gr < OHH)
      v = R[((size_t)(b * CCH + c) << 12) + (gr << 6) + cc];
    Rl[c][rr][cc] = v;
  }
  __syncthreads();
  int x = tid & 63, yg = tid >> 6;
  int yb = yg * 4;
  double acc[8][4];
#pragma unroll
  for (int aa = 0; aa < 8; ++aa)
#pragma unroll
    for (int ty = 0; ty < 4; ++ty) acc[aa][ty] = 0.0;

  for (int c = 0; c < 3; ++c) {
#pragma unroll
    for (int j = 0; j < 8; ++j) {
      double rw[11];
#pragma unroll
      for (int r = 0; r < 11; ++r) rw[r] = (double)Rl[c][yb + r][x + j];
#pragma unroll
      for (int i = 0; i < 8; ++i) {
        const float* wp = &Wl[((c * 8 + i) * 8 + j) * 8];
#pragma unroll
        for (int aa = 0; aa < 8; ++aa) {
          double w = (double)wp[aa];
          acc[aa][0] = fma(rw[i + 0], w, acc[aa][0]);
          acc[aa][1] = fma(rw[i + 1], w, acc[aa][1]);
          acc[aa][2] = fma(rw[i + 2], w, acc[aa][2]);
          acc[aa][3] = fma(rw[i + 3], w, acc[aa][3]);
        }
      }
    }
  }
  if (x < XW) {
    int gy0 = row0 + yb;
#pragma unroll
    for (int ty = 0; ty < 4; ++ty) {
      int yy = gy0 + ty;
      if (yy < XH) {
#pragma unroll
        for (int aa = 0; aa < 8; ++aa) {
          size_t xo = (size_t)(b * ATOMS + a0 + aa) * PIX + yy * XW + x;
          float fv = (float)((double)Xprev[xo] - acc[aa][ty]);
          HT[xo] = fv;
          unsigned u = __float_as_uint(fv) & 0x7fffffffu;
          atomicAdd(&hh[u >> 20], 1u);
        }
      }
    }
  }
  __syncthreads();
  unsigned* gp = g1 + (size_t)b * 2048;
  for (int e = tid; e < 2048; e += 256)
    if (hh[e]) atomicAdd(&gp[e], hh[e]);
}

// Find bin containing rank Kv (descending); Kin==nullptr -> KSEL.
template <int NB>
__global__ __launch_bounds__(256) void find_k(const unsigned* __restrict__ gh,
    const int* __restrict__ Kin, int* __restrict__ Bout, int* __restrict__ Kout) {
  int s = blockIdx.x;
  const unsigned* h = gh + s * NB;
  __shared__ unsigned part[256];
  constexpr int C = NB / 256;
  int t = threadIdx.x;
  unsigned sum = 0;
#pragma unroll
  for (int e = 0; e < C; ++e) sum += h[t * C + e];
  part[t] = sum;
  __syncthreads();
  if (t == 0) {
    int Kv = Kin ? Kin[s] : KSEL;
    unsigned cumBefore = 0;
    int bsel = 0;
    for (int q = 255; q >= 0; --q) {
      unsigned ps = part[q];
      if ((int)(cumBefore + ps) >= Kv) {
        for (int e = q * C + C - 1;; --e) {
          unsigned c2 = cumBefore + h[e];
          if ((int)c2 >= Kv) { bsel = e; break; }
          cumBefore = c2;
        }
        break;
      }
      cumBefore += ps;
    }
    Bout[s] = bsel;
    Kout[s] = Kv - (int)cumBefore;
  }
}

// ---------------------------------------------------------------------------
// Level 2: float4 scan; histogram next 10 bits within bin b1 + gather cands.
// Per-block LDS candidate aggregation: ONE global atomic per block (was:
// one per candidate -> ~1.4-4K serialized RMWs/sample = 250us).
// ---------------------------------------------------------------------------
__global__ __launch_bounds__(256) void hist2_k(const float* __restrict__ HT,
    const int* __restrict__ b1, unsigned* __restrict__ g2,
    int* __restrict__ cand, int* __restrict__ candcnt) {
  __shared__ unsigned h[1024];
  __shared__ int lidx[4096];
  __shared__ int lcnt, lbase;
  for (int e = threadIdx.x; e < 1024; e += 256) h[e] = 0;
  if (threadIdx.x == 0) lcnt = 0;
  __syncthreads();
  int s = blockIdx.x >> 5;
  int chunk = blockIdx.x & 31;
  unsigned pre = (unsigned)b1[s];
  const uint4* U4 = (const uint4*)(HT + (size_t)s * NPS);
  for (int i4 = chunk * 256 + threadIdx.x; i4 < NPS / 4; i4 += 32 * 256) {
    uint4 v = U4[i4];
    unsigned uu[4] = {v.x, v.y, v.z, v.w};
#pragma unroll
    for (int t = 0; t < 4; ++t) {
      unsigned u = uu[t] & 0x7fffffffu;
      if ((u >> 20) == pre) {
        atomicAdd(&h[(u >> 10) & 1023], 1u);
        int pos = atomicAdd(&lcnt, 1);           // LDS atomic, cheap
        if (pos < 4096) lidx[pos] = i4 * 4 + t;
      }
    }
  }
  __syncthreads();
  if (threadIdx.x == 0) {
    int n = lcnt < 4096 ? lcnt : 4096;
    lbase = atomicAdd(&candcnt[s], n);           // ONE global atomic/block
  }
  __syncthreads();
  int n = lcnt < 4096 ? lcnt : 4096;
  int base = lbase;
  for (int e = threadIdx.x; e < n; e += 256) {
    int g = base + e;
    if (g < CANDCAP) cand[s * CANDCAP + g] = lidx[e];
  }
  for (int e = threadIdx.x; e < 1024; e += 256)
    if (h[e]) atomicAdd(&g2[s * 1024 + e], h[e]);
}

// Level 3 + tie resolution over candidate list (one block per sample).
__global__ __launch_bounds__(256) void pass3_k(const float* __restrict__ HT,
    const int* __restrict__ cand, const int* __restrict__ candcnt,
    const int* __restrict__ b1, const int* __restrict__ b2,
    const int* __restrict__ k2, unsigned* __restrict__ tau_out,
    int* __restrict__ cutoff_out) {
  int s = blockIdx.x;
  __shared__ unsigned h[1024];
  __shared__ int eqidx[1024];
  __shared__ int eqn;
  __shared__ unsigned tau_sh;
  __shared__ int k3_sh;
  for (int e = threadIdx.x; e < 1024; e += 256) h[e] = 0;
  if (threadIdx.x == 0) eqn = 0;
  __syncthreads();
  int n = candcnt[s];
  if (n > CANDCAP) n = CANDCAP;
  unsigned pre21 = (((unsigned)b1[s]) << 10) | (unsigned)b2[s];
  const unsigned* U = (const unsigned*)(HT + (size_t)s * NPS);
  for (int t = threadIdx.x; t < n; t += 256) {
    int i = cand[s * CANDCAP + t];
    unsigned u = U[i] & 0x7fffffffu;
    if ((u >> 10) == pre21) atomicAdd(&h[u & 1023], 1u);
  }
  __syncthreads();
  if (threadIdx.x == 0) {
    int Kv = k2[s];
    unsigned cumBefore = 0;
    int b3 = 0;
    for (int e = 1023; e >= 0; --e) {
      unsigned c2 = cumBefore + h[e];
      if ((int)c2 >= Kv) { b3 = e; break; }
      cumBefore = c2;
    }
    tau_sh = (pre21 << 10) | (unsigned)b3;
    k3_sh = Kv - (int)cumBefore;
  }
  __syncthreads();
  unsigned tau = tau_sh;
  for (int t = threadIdx.x; t < n; t += 256) {
    int i = cand[s * CANDCAP + t];
    unsigned u = U[i] & 0x7fffffffu;
    if (u == tau) {
      int pos = atomicAdd(&eqn, 1);
      if (pos < 1024) eqidx[pos] = i;
    }
  }
  __syncthreads();
  if (threadIdx.x == 0) {
    int m = eqn < 1024 ? eqn : 1024;
    int k3 = k3_sh;
    int cutoff;
    if (k3 >= m) {
      cutoff = 0x7fffffff;
    } else {
      int last = -1;
      for (int r = 0; r < k3; ++r) {
        int mn = 0x7fffffff;
        for (int q = 0; q < m; ++q) {
          int v = eqidx[q];
          if (v > last && v < mn) mn = v;
        }
        last = mn;
      }
      cutoff = last;
    }
    tau_out[s] = tau;
    cutoff_out[s] = cutoff;
  }
}

// ---------------------------------------------------------------------------
// Threshold write (float4) + nz-list emit, per-block LDS aggregation.
// ---------------------------------------------------------------------------
__global__ __launch_bounds__(256) void write_k(const float* __restrict__ HT,
    const unsigned* __restrict__ tau, const int* __restrict__ cutoff,
    float* __restrict__ Xo, int* __restrict__ nzidx, float* __restrict__ nzval,
    int* __restrict__ nzcnt) {
  __shared__ int lidx[2048];
  __shared__ float lval[2048];
  __shared__ int lcnt, lbase;
  int s = blockIdx.x / WSEG;
  int seg = blockIdx.x % WSEG;
  int tid = threadIdx.x;
  if (tid == 0) lcnt = 0;
  __syncthreads();
  unsigned tt = tau[s];
  int co = cutoff[s];
  size_t sbase = (size_t)s * NPS;
  const float4* H4 = (const float4*)(HT + sbase);
  float4* X4 = (float4*)(Xo + sbase);
  int f0 = seg * 1024;
#pragma unroll
  for (int rr = 0; rr < 4; ++rr) {
    int i4 = f0 + rr * 256 + tid;
    if (i4 < NPS / 4) {
      float4 v = H4[i4];
      float vv[4] = {v.x, v.y, v.z, v.w};
      float oo[4];
#pragma unroll
      for (int t = 0; t < 4; ++t) {
        int il = i4 * 4 + t;
        unsigned u = __float_as_uint(vv[t]) & 0x7fffffffu;
        bool keep = (u > tt) || (u == tt && il <= co);
        oo[t] = keep ? vv[t] : 0.0f;
        if (keep) {
          int pos = atomicAdd(&lcnt, 1);
          if (pos < 2048) { lidx[pos] = il; lval[pos] = vv[t]; }
        }
      }
      X4[i4] = make_float4(oo[0], oo[1], oo[2], oo[3]);
    }
  }
  __syncthreads();
  if (tid == 0) lbase = atomicAdd(&nzcnt[s], lcnt);
  __syncthreads();
  int n = lcnt < 2048 ? lcnt : 2048;
  int base = lbase;
  for (int e = tid; e < n; e += 256) {
    int g = base + e;
    if (g < KSEL) { nzidx[s * KSEL + g] = lidx[e]; nzval[s * KSEL + g] = lval[e]; }
  }
}

extern "C" void kernel_launch(void* const* d_in, const int* in_sizes, int n_in,
                              void* d_out, int out_size, void* d_ws, size_t ws_size,
                              hipStream_t stream) {
  const float* Y  = (const float*)d_in[0];
  const float* X0 = (const float*)d_in[1];
  const float* Wg = (const float*)d_in[2];
  float* Xout = (float*)d_out;

  double* WDd  = (double*)d_ws;                        // NW f64
  float* HT   = (float*)(WDd + NW);                    // NTOT f32
  float* Rbuf = HT + NTOT;                             // RTOT f32
  double* Rd  = (double*)(Rbuf + RTOT);                // RTOT f64
  unsigned* g1 = (unsigned*)(Rd + RTOT);               // 32*2048
  unsigned* g2 = g1 + 32 * 2048;                       // 32*1024
  int* candcnt = (int*)(g2 + 32 * 1024);               // 32
  int* nzcnt = candcnt + 32;                           // 32
  int* b1 = nzcnt + 32;
  int* k1 = b1 + 32;
  int* b2 = k1 + 32;
  int* k2 = b2 + 32;
  unsigned* tau = (unsigned*)(k2 + 32);
  int* cutoff = (int*)(tau + 32);
  int* cand = cutoff + 32;                             // 32*CANDCAP
  int* nzidx = cand + 32 * CANDCAP;                    // 32*KSEL
  float* nzval = (float*)(nzidx + 32 * KSEL);          // 32*KSEL
  size_t zero_bytes = (size_t)(32 * 2048 + 32 * 1024 + 32 + 32) * 4;

  wprep_k<<<dim3((NW + 255) / 256), dim3(256), 0, stream>>>(Wg, WDd);

  for (int it = 0; it < 3; ++it) {
    const float* Xsrc = (it == 0) ? X0 : (const float*)Xout;
    hipMemsetAsync(g1, 0, zero_bytes, stream);  // g1, g2, candcnt, nzcnt
    if (it == 0) {
      rinit_k<<<dim3((RTOT + 255) / 256), dim3(256), 0, stream>>>(Y, Rd);
      convD_k<<<dim3(1024), dim3(256), 0, stream>>>(Xsrc, WDd, Rd);
      rfin_k<<<dim3((RTOT + 255) / 256), dim3(256), 0, stream>>>(Rd, Rbuf);
    } else {
      convD_sparse_k<<<dim3(BATCH * CCH * 8), dim3(256), 0, stream>>>(
          Wg, nzidx, nzval, Y, Rbuf);
    }
    convDt_k<<<dim3(2048), dim3(256), 0, stream>>>(Rbuf, Wg, Xsrc, HT, g1);
    find_k<2048><<<dim3(BATCH), dim3(256), 0, stream>>>(g1, (const int*)nullptr, b1, k1);
    hist2_k<<<dim3(BATCH * 32), dim3(256), 0, stream>>>(HT, b1, g2, cand, candcnt);
    find_k<1024><<<dim3(BATCH), dim3(256), 0, stream>>>(g2, k1, b2, k2);
    pass3_k<<<dim3(BATCH), dim3(256), 0, stream>>>(HT, cand, candcnt, b1, b2, k2, tau, cutoff);
    write_k<<<dim3(BATCH * WSEG), dim3(256), 0, stream>>>(HT, tau, cutoff, Xout,
                                                          nzidx, nzval, nzcnt);
  }
}

// Round 7
// 1078.134 us; speedup vs baseline: 5.9001x; 1.0913x over previous
//
#include <hip/hip_runtime.h>

#define BATCH 32
#define ATOMS 128
#define CCH 3
#define XH 57
#define XW 57
#define OHH 64
#define OWW 64
#define KSEL 2000
#define PIX (XH*XW)            // 3249
#define NPS (ATOMS*PIX)        // 415872 per-sample X elements
#define NTOT (BATCH*NPS)       // 13307904
#define RPS (CCH*OHH*OWW)      // 12288 per-sample R elements
#define RTOT (BATCH*RPS)       // 393216
#define CANDCAP 32768
#define NW 24576               // weight elements 128*3*8*8
#define WSEG 102               // write_k segments of 1024 float4 per sample

// ---------------------------------------------------------------------------
// Weight prep (once): WDd[a][kh][c][kw] f64 (convD), Wt2d[c][i][j][a] f64
// (convDt, contiguous 8 f64 per (c,i,j,atom-group) -> s_load_dwordx16).
// ---------------------------------------------------------------------------
__global__ __launch_bounds__(256) void wprep_k(const float* __restrict__ Wg,
    double* __restrict__ WDd, double* __restrict__ Wt2d) {
  int e = blockIdx.x * 256 + threadIdx.x;
  if (e >= NW) return;
  {
    int kw = e & 7; int t = e >> 3; int c = t % 3; t /= 3; int kh = t & 7; int a = t >> 3;
    WDd[e] = (double)Wg[(a*3 + c)*64 + kh*8 + kw];
  }
  {
    int a = e & 127; int t = e >> 7; int j = t & 7; int i = (t >> 3) & 7; int c = t >> 6;
    Wt2d[e] = (double)Wg[(a*3 + c)*64 + j*8 + i];
  }
}

// Rd = -Y (f64), dense-path init.
__global__ __launch_bounds__(256) void rinit_k(const float* __restrict__ Y,
    double* __restrict__ Rd) {
  int i = blockIdx.x * 256 + threadIdx.x;
  if (i < RTOT) Rd[i] = -(double)Y[i];
}

// R = (float)Rd, dense-path finish.
__global__ __launch_bounds__(256) void rfin_k(const double* __restrict__ Rd,
    float* __restrict__ R) {
  int i = blockIdx.x * 256 + threadIdx.x;
  if (i < RTOT) R[i] = (float)Rd[i];
}

// ---------------------------------------------------------------------------
// DENSE R += D(X) (iteration 0 only). Block = (b, 2-row band, atom-half).
// grid = 2048 (8 blocks/CU schedulable; LDS 20.7KB -> 7 resident).
// 8 chunks x 8 atoms staged in LDS; wave wv handles atoms wv*2, wv*2+1.
// acc[2][3] f64 (~45 VGPR). Direct f64 atomics into Rd (8 contrib/addr).
// ---------------------------------------------------------------------------
__global__ __launch_bounds__(256) void convD_k(const float* __restrict__ X,
    const double* __restrict__ WDd, double* __restrict__ Rd) {
  __shared__ float Xs[8][9][72];              // 20736 B
  int p = blockIdx.x;
  int lg = (p & 7) * 256 + (p >> 3);          // bijective: 2048 = 8*256
  int b = lg >> 6; int rem = lg & 63;
  int band = rem >> 1, half = rem & 1;
  int oy0 = band * 2;
  int a_base = half * 64;
  int tid = threadIdx.x;
  int ox = tid & 63;
  int wv = __builtin_amdgcn_readfirstlane(tid >> 6);
  const float* Xb = X + (size_t)b * NPS;

  double acc[2][3];
#pragma unroll
  for (int ty = 0; ty < 2; ++ty)
#pragma unroll
    for (int c = 0; c < 3; ++c) acc[ty][c] = 0.0;

  for (int ch = 0; ch < 8; ++ch) {
    __syncthreads();
    for (int e = tid; e < 8 * 9 * 72; e += 256) {
      int ai = e / 648; int rem2 = e - ai * 648;
      int r = rem2 / 72; int ss = rem2 - r * 72;
      int gy = oy0 - 7 + r;
      int xcol = ss - 7;
      int a = a_base + ch * 8 + ai;
      float v = 0.0f;
      if ((unsigned)xcol < (unsigned)XW && (unsigned)gy < (unsigned)XH)
        v = Xb[a * PIX + gy * XW + xcol];
      Xs[ai][r][ss] = v;
    }
    __syncthreads();
#pragma unroll
    for (int jj = 0; jj < 2; ++jj) {
      int ai = (wv << 1) + jj;
      int a  = a_base + ch * 8 + ai;
      const double* Wa = WDd + a * 192;       // [kh][c][kw]
      for (int r = 0; r < 9; ++r) {
        int gy = oy0 - 7 + r;
        if ((unsigned)gy >= (unsigned)XH) continue;   // uniform
        double xd[8];
#pragma unroll
        for (int t = 0; t < 8; ++t) xd[t] = (double)Xs[ai][r][ox + t];
        if (r <= 7) {                          // ty=0, kh = 7-r
          const double* Wk = Wa + (7 - r) * 24;
#pragma unroll
          for (int kw = 0; kw < 8; ++kw) {
            acc[0][0] = fma(xd[7 - kw], Wk[kw],      acc[0][0]);
            acc[0][1] = fma(xd[7 - kw], Wk[8 + kw],  acc[0][1]);
            acc[0][2] = fma(xd[7 - kw], Wk[16 + kw], acc[0][2]);
          }
        }
        if (r >= 1) {                          // ty=1, kh = 8-r
          const double* Wk = Wa + (8 - r) * 24;
#pragma unroll
          for (int kw = 0; kw < 8; ++kw) {
            acc[1][0] = fma(xd[7 - kw], Wk[kw],      acc[1][0]);
            acc[1][1] = fma(xd[7 - kw], Wk[8 + kw],  acc[1][1]);
            acc[1][2] = fma(xd[7 - kw], Wk[16 + kw], acc[1][2]);
          }
        }
      }
    }
  }
#pragma unroll
  for (int ty = 0; ty < 2; ++ty) {
    int oy = oy0 + ty;
#pragma unroll
    for (int c = 0; c < 3; ++c)
      atomicAdd(&Rd[((size_t)(b * CCH + c) << 12) + (oy << 6) + ox], acc[ty][c]);
  }
}

// ---------------------------------------------------------------------------
// SPARSE R = D(X) - Y (iterations 1,2). Unchanged from round 6.
// ---------------------------------------------------------------------------
__global__ __launch_bounds__(256) void convD_sparse_k(const float* __restrict__ Wg,
    const int* __restrict__ nzidx, const float* __restrict__ nzval,
    const float* __restrict__ Y, float* __restrict__ R) {
  __shared__ double accd[512];       // [rr][ox]
  __shared__ float Wf[8192];         // [a][kh][kw] for this c
  __shared__ int   li[KSEL];
  __shared__ float lv[KSEL];
  int p = blockIdx.x;
  int lg = (p & 7) * 96 + (p >> 3);  // bijective: 768 = 8*96
  int s = lg / 24; int r = lg % 24; int c = r >> 3; int band = r & 7;
  int row0 = band * 8;
  int tid = threadIdx.x;
  for (int e = tid; e < 512; e += 256) accd[e] = 0.0;
  for (int e = tid; e < 8192; e += 256) {
    int a = e >> 6, k2 = e & 63;
    Wf[e] = Wg[(a * 3 + c) * 64 + k2];
  }
  for (int e = tid; e < KSEL; e += 256) {
    li[e] = nzidx[s * KSEL + e];
    lv[e] = nzval[s * KSEL + e];
  }
  __syncthreads();
  int slot = tid >> 3, kw = tid & 7;
  for (int e = slot; e < KSEL; e += 32) {
    int idx = li[e];
    int a = (int)((unsigned)idx / 3249u);
    int pp = idx - a * 3249;
    int y = (int)((unsigned)pp / 57u);
    int x = pp - y * 57;
    int dy = y - row0;
    if (dy < -7 || dy > 7) continue;
    double val = (double)lv[e];
    const float* wp = Wf + (a << 6) + kw;
#pragma unroll
    for (int kh = 0; kh < 8; ++kh) {
      int rr = dy + kh;
      if ((unsigned)rr < 8u)
        __hip_atomic_fetch_add(&accd[(rr << 6) + x + kw],
                               val * (double)wp[kh << 3],
                               __ATOMIC_RELAXED, __HIP_MEMORY_SCOPE_WORKGROUP);
    }
  }
  __syncthreads();
  const float* Yb = Y + (((size_t)(s * CCH + c)) << 12) + (row0 << 6);
  float* Rb = R + (((size_t)(s * CCH + c)) << 12) + (row0 << 6);
  for (int e = tid; e < 512; e += 256)
    Rb[e] = (float)(accd[e] - (double)Yb[e]);
}

// ---------------------------------------------------------------------------
// HT = Xprev - Dt(R), f64. Block = (b, 8-atom group, 8-row band); thread =
// 8 atoms x 2 rows (acc[8][2]=32 regs, rw[9]=18 -> ~60 VGPR target).
// Weights via wave-uniform f64 s_load from Wt2d (no cvt, no LDS, scalar pipe).
// Fused level-1 hist, packed u16 (max 4096/bin/block). grid = 4096.
// LDS = 12.9K Rl + 4K hist = 17KB.
// ---------------------------------------------------------------------------
__global__ __launch_bounds__(256) void convDt_k(const float* __restrict__ R,
    const double* __restrict__ Wt2d, const float* __restrict__ Xprev,
    float* __restrict__ HT, unsigned* __restrict__ g1) {
  __shared__ float Rl[3][15][72];
  __shared__ unsigned hh[1024];      // packed: 2 u16 bins per word
  int p = blockIdx.x;
  int lg = (p & 7) * 512 + (p >> 3);  // bijective: 4096 = 8*512
  int b = lg >> 7; int rem = lg & 127; int ag = rem >> 3; int by = rem & 7;
  int row0 = by * 8;
  int a0 = ag * 8;
  int tid = threadIdx.x;
  for (int e = tid; e < 1024; e += 256) hh[e] = 0;
  for (int e = tid; e < 3 * 15 * 72; e += 256) {
    int c = e / (15 * 72); int r2 = e - c * (15 * 72);
    int rr = r2 / 72; int cc = r2 - rr * 72;
    int gr = row0 + rr;
    float v = 0.0f;
    if (cc < OWW && gr < OHH)
      v = R[((size_t)(b * CCH + c) << 12) + (gr << 6) + cc];
    Rl[c][rr][cc] = v;
  }
  __syncthreads();
  int x = tid & 63, yg = tid >> 6;
  int yb = yg * 2;
  double acc[8][2];
#pragma unroll
  for (int aa = 0; aa < 8; ++aa) { acc[aa][0] = 0.0; acc[aa][1] = 0.0; }

#pragma unroll 1
  for (int c = 0; c < 3; ++c) {
#pragma unroll 1
    for (int j = 0; j < 8; ++j) {
      double rw[9];
#pragma unroll
      for (int r = 0; r < 9; ++r) rw[r] = (double)Rl[c][yb + r][x + j];
#pragma unroll
      for (int i = 0; i < 8; ++i) {
        const double* wp = Wt2d + ((c * 8 + i) * 8 + j) * 128 + a0;  // uniform
#pragma unroll
        for (int aa = 0; aa < 8; ++aa) {
          double w = wp[aa];
          acc[aa][0] = fma(rw[i + 0], w, acc[aa][0]);
          acc[aa][1] = fma(rw[i + 1], w, acc[aa][1]);
        }
      }
    }
  }
  if (x < XW) {
#pragma unroll
    for (int ty = 0; ty < 2; ++ty) {
      int yy = row0 + yb + ty;
      if (yy < XH) {
#pragma unroll
        for (int aa = 0; aa < 8; ++aa) {
          size_t xo = (size_t)(b * ATOMS + a0 + aa) * PIX + yy * XW + x;
          float fv = (float)((double)Xprev[xo] - acc[aa][ty]);
          HT[xo] = fv;
          unsigned u = __float_as_uint(fv) & 0x7fffffffu;
          unsigned bin = u >> 20;
          atomicAdd(&hh[bin >> 1], 1u << ((bin & 1) << 4));
        }
      }
    }
  }
  __syncthreads();
  unsigned* gp = g1 + (size_t)b * 2048;
  for (int e = tid; e < 1024; e += 256) {
    unsigned v = hh[e];
    unsigned lo = v & 0xffffu, hi = v >> 16;
    if (lo) atomicAdd(&gp[2 * e], lo);
    if (hi) atomicAdd(&gp[2 * e + 1], hi);
  }
}

// Find bin containing rank Kv (descending); Kin==nullptr -> KSEL.
template <int NB>
__global__ __launch_bounds__(256) void find_k(const unsigned* __restrict__ gh,
    const int* __restrict__ Kin, int* __restrict__ Bout, int* __restrict__ Kout) {
  int s = blockIdx.x;
  const unsigned* h = gh + s * NB;
  __shared__ unsigned part[256];
  constexpr int C = NB / 256;
  int t = threadIdx.x;
  unsigned sum = 0;
#pragma unroll
  for (int e = 0; e < C; ++e) sum += h[t * C + e];
  part[t] = sum;
  __syncthreads();
  if (t == 0) {
    int Kv = Kin ? Kin[s] : KSEL;
    unsigned cumBefore = 0;
    int bsel = 0;
    for (int q = 255; q >= 0; --q) {
      unsigned ps = part[q];
      if ((int)(cumBefore + ps) >= Kv) {
        for (int e = q * C + C - 1;; --e) {
          unsigned c2 = cumBefore + h[e];
          if ((int)c2 >= Kv) { bsel = e; break; }
          cumBefore = c2;
        }
        break;
      }
      cumBefore += ps;
    }
    Bout[s] = bsel;
    Kout[s] = Kv - (int)cumBefore;
  }
}

// ---------------------------------------------------------------------------
// Level 2: float4 scan; per-block LDS candidate aggregation (one global
// atomic per block). Unchanged from round 6.
// ---------------------------------------------------------------------------
__global__ __launch_bounds__(256) void hist2_k(const float* __restrict__ HT,
    const int* __restrict__ b1, unsigned* __restrict__ g2,
    int* __restrict__ cand, int* __restrict__ candcnt) {
  __shared__ unsigned h[1024];
  __shared__ int lidx[4096];
  __shared__ int lcnt, lbase;
  for (int e = threadIdx.x; e < 1024; e += 256) h[e] = 0;
  if (threadIdx.x == 0) lcnt = 0;
  __syncthreads();
  int s = blockIdx.x >> 5;
  int chunk = blockIdx.x & 31;
  unsigned pre = (unsigned)b1[s];
  const uint4* U4 = (const uint4*)(HT + (size_t)s * NPS);
  for (int i4 = chunk * 256 + threadIdx.x; i4 < NPS / 4; i4 += 32 * 256) {
    uint4 v = U4[i4];
    unsigned uu[4] = {v.x, v.y, v.z, v.w};
#pragma unroll
    for (int t = 0; t < 4; ++t) {
      unsigned u = uu[t] & 0x7fffffffu;
      if ((u >> 20) == pre) {
        atomicAdd(&h[(u >> 10) & 1023], 1u);
        int pos = atomicAdd(&lcnt, 1);           // LDS atomic, cheap
        if (pos < 4096) lidx[pos] = i4 * 4 + t;
      }
    }
  }
  __syncthreads();
  if (threadIdx.x == 0) {
    int n = lcnt < 4096 ? lcnt : 4096;
    lbase = atomicAdd(&candcnt[s], n);           // ONE global atomic/block
  }
  __syncthreads();
  int n = lcnt < 4096 ? lcnt : 4096;
  int base = lbase;
  for (int e = threadIdx.x; e < n; e += 256) {
    int g = base + e;
    if (g < CANDCAP) cand[s * CANDCAP + g] = lidx[e];
  }
  for (int e = threadIdx.x; e < 1024; e += 256)
    if (h[e]) atomicAdd(&g2[s * 1024 + e], h[e]);
}

// ---------------------------------------------------------------------------
// Fused level-2 rank find + level 3 + tie resolution (one block per sample).
// ---------------------------------------------------------------------------
__global__ __launch_bounds__(256) void pass3_k(const float* __restrict__ HT,
    const int* __restrict__ cand, const int* __restrict__ candcnt,
    const int* __restrict__ b1, const unsigned* __restrict__ g2,
    const int* __restrict__ k1, unsigned* __restrict__ tau_out,
    int* __restrict__ cutoff_out) {
  int s = blockIdx.x;
  __shared__ unsigned h[1024];
  __shared__ unsigned part[256];
  __shared__ int eqidx[1024];
  __shared__ int eqn;
  __shared__ unsigned tau_sh;
  __shared__ int k3_sh;
  __shared__ int b2_sh, k2_sh;
  int t = threadIdx.x;
  // ---- find2 over g2[1024] (was find_k<1024>) ----
  const unsigned* hg = g2 + s * 1024;
  unsigned sum = 0;
#pragma unroll
  for (int e = 0; e < 4; ++e) sum += hg[t * 4 + e];
  part[t] = sum;
  for (int e = t; e < 1024; e += 256) h[e] = 0;
  if (t == 0) eqn = 0;
  __syncthreads();
  if (t == 0) {
    int Kv = k1[s];
    unsigned cumBefore = 0;
    int bsel = 0;
    for (int q = 255; q >= 0; --q) {
      unsigned ps = part[q];
      if ((int)(cumBefore + ps) >= Kv) {
        for (int e = q * 4 + 3;; --e) {
          unsigned c2 = cumBefore + hg[e];
          if ((int)c2 >= Kv) { bsel = e; break; }
          cumBefore = c2;
        }
        break;
      }
      cumBefore += ps;
    }
    b2_sh = bsel;
    k2_sh = Kv - (int)cumBefore;
  }
  __syncthreads();
  // ---- level 3 over candidates ----
  int n = candcnt[s];
  if (n > CANDCAP) n = CANDCAP;
  unsigned pre21 = (((unsigned)b1[s]) << 10) | (unsigned)b2_sh;
  const unsigned* U = (const unsigned*)(HT + (size_t)s * NPS);
  for (int e = t; e < n; e += 256) {
    int i = cand[s * CANDCAP + e];
    unsigned u = U[i] & 0x7fffffffu;
    if ((u >> 10) == pre21) atomicAdd(&h[u & 1023], 1u);
  }
  __syncthreads();
  if (t == 0) {
    int Kv = k2_sh;
    unsigned cumBefore = 0;
    int b3 = 0;
    for (int e = 1023; e >= 0; --e) {
      unsigned c2 = cumBefore + h[e];
      if ((int)c2 >= Kv) { b3 = e; break; }
      cumBefore = c2;
    }
    tau_sh = (pre21 << 10) | (unsigned)b3;
    k3_sh = Kv - (int)cumBefore;
  }
  __syncthreads();
  unsigned tau = tau_sh;
  for (int e = t; e < n; e += 256) {
    int i = cand[s * CANDCAP + e];
    unsigned u = U[i] & 0x7fffffffu;
    if (u == tau) {
      int pos = atomicAdd(&eqn, 1);
      if (pos < 1024) eqidx[pos] = i;
    }
  }
  __syncthreads();
  if (t == 0) {
    int m = eqn < 1024 ? eqn : 1024;
    int k3 = k3_sh;
    int cutoff;
    if (k3 >= m) {
      cutoff = 0x7fffffff;
    } else {
      int last = -1;
      for (int r = 0; r < k3; ++r) {
        int mn = 0x7fffffff;
        for (int q = 0; q < m; ++q) {
          int v = eqidx[q];
          if (v > last && v < mn) mn = v;
        }
        last = mn;
      }
      cutoff = last;
    }
    tau_out[s] = tau;
    cutoff_out[s] = cutoff;
  }
}

// ---------------------------------------------------------------------------
// Threshold write (float4) + nz-list emit, per-block LDS aggregation.
// ---------------------------------------------------------------------------
__global__ __launch_bounds__(256) void write_k(const float* __restrict__ HT,
    const unsigned* __restrict__ tau, const int* __restrict__ cutoff,
    float* __restrict__ Xo, int* __restrict__ nzidx, float* __restrict__ nzval,
    int* __restrict__ nzcnt) {
  __shared__ int lidx[2048];
  __shared__ float lval[2048];
  __shared__ int lcnt, lbase;
  int s = blockIdx.x / WSEG;
  int seg = blockIdx.x % WSEG;
  int tid = threadIdx.x;
  if (tid == 0) lcnt = 0;
  __syncthreads();
  unsigned tt = tau[s];
  int co = cutoff[s];
  size_t sbase = (size_t)s * NPS;
  const float4* H4 = (const float4*)(HT + sbase);
  float4* X4 = (float4*)(Xo + sbase);
  int f0 = seg * 1024;
#pragma unroll
  for (int rr = 0; rr < 4; ++rr) {
    int i4 = f0 + rr * 256 + tid;
    if (i4 < NPS / 4) {
      float4 v = H4[i4];
      float vv[4] = {v.x, v.y, v.z, v.w};
      float oo[4];
#pragma unroll
      for (int t = 0; t < 4; ++t) {
        int il = i4 * 4 + t;
        unsigned u = __float_as_uint(vv[t]) & 0x7fffffffu;
        bool keep = (u > tt) || (u == tt && il <= co);
        oo[t] = keep ? vv[t] : 0.0f;
        if (keep) {
          int pos = atomicAdd(&lcnt, 1);
          if (pos < 2048) { lidx[pos] = il; lval[pos] = vv[t]; }
        }
      }
      X4[i4] = make_float4(oo[0], oo[1], oo[2], oo[3]);
    }
  }
  __syncthreads();
  if (tid == 0) lbase = atomicAdd(&nzcnt[s], lcnt);
  __syncthreads();
  int n = lcnt < 2048 ? lcnt : 2048;
  int base = lbase;
  for (int e = tid; e < n; e += 256) {
    int g = base + e;
    if (g < KSEL) { nzidx[s * KSEL + g] = lidx[e]; nzval[s * KSEL + g] = lval[e]; }
  }
}

extern "C" void kernel_launch(void* const* d_in, const int* in_sizes, int n_in,
                              void* d_out, int out_size, void* d_ws, size_t ws_size,
                              hipStream_t stream) {
  const float* Y  = (const float*)d_in[0];
  const float* X0 = (const float*)d_in[1];
  const float* Wg = (const float*)d_in[2];
  float* Xout = (float*)d_out;

  double* WDd  = (double*)d_ws;                        // NW f64
  double* Wt2d = WDd + NW;                             // NW f64
  float* HT   = (float*)(Wt2d + NW);                   // NTOT f32
  float* Rbuf = HT + NTOT;                             // RTOT f32
  double* Rd  = (double*)(Rbuf + RTOT);                // RTOT f64
  unsigned* g1 = (unsigned*)(Rd + RTOT);               // 32*2048
  unsigned* g2 = g1 + 32 * 2048;                       // 32*1024
  int* candcnt = (int*)(g2 + 32 * 1024);               // 32
  int* nzcnt = candcnt + 32;                           // 32
  int* b1 = nzcnt + 32;
  int* k1 = b1 + 32;
  unsigned* tau = (unsigned*)(k1 + 32);
  int* cutoff = (int*)(tau + 32);
  int* cand = cutoff + 32;                             // 32*CANDCAP
  int* nzidx = cand + 32 * CANDCAP;                    // 32*KSEL
  float* nzval = (float*)(nzidx + 32 * KSEL);          // 32*KSEL
  size_t zero_bytes = (size_t)(32 * 2048 + 32 * 1024 + 32 + 32) * 4;

  wprep_k<<<dim3((NW + 255) / 256), dim3(256), 0, stream>>>(Wg, WDd, Wt2d);

  for (int it = 0; it < 3; ++it) {
    const float* Xsrc = (it == 0) ? X0 : (const float*)Xout;
    hipMemsetAsync(g1, 0, zero_bytes, stream);  // g1, g2, candcnt, nzcnt
    if (it == 0) {
      rinit_k<<<dim3((RTOT + 255) / 256), dim3(256), 0, stream>>>(Y, Rd);
      convD_k<<<dim3(2048), dim3(256), 0, stream>>>(Xsrc, WDd, Rd);
      rfin_k<<<dim3((RTOT + 255) / 256), dim3(256), 0, stream>>>(Rd, Rbuf);
    } else {
      convD_sparse_k<<<dim3(BATCH * CCH * 8), dim3(256), 0, stream>>>(
          Wg, nzidx, nzval, Y, Rbuf);
    }
    convDt_k<<<dim3(4096), dim3(256), 0, stream>>>(Rbuf, Wt2d, Xsrc, HT, g1);
    find_k<2048><<<dim3(BATCH), dim3(256), 0, stream>>>(g1, (const int*)nullptr, b1, k1);
    hist2_k<<<dim3(BATCH * 32), dim3(256), 0, stream>>>(HT, b1, g2, cand, candcnt);
    pass3_k<<<dim3(BATCH), dim3(256), 0, stream>>>(HT, cand, candcnt, b1, g2, k1, tau, cutoff);
    write_k<<<dim3(BATCH * WSEG), dim3(256), 0, stream>>>(HT, tau, cutoff, Xout,
                                                          nzidx, nzval, nzcnt);
  }
}

// Round 8
// 1006.229 us; speedup vs baseline: 6.3217x; 1.0715x over previous
//
#include <hip/hip_runtime.h>

#define BATCH 32
#define ATOMS 128
#define CCH 3
#define XH 57
#define XW 57
#define OHH 64
#define OWW 64
#define KSEL 2000
#define PIX (XH*XW)            // 3249
#define NPS (ATOMS*PIX)        // 415872 per-sample X elements
#define NTOT (BATCH*NPS)       // 13307904
#define RPS (CCH*OHH*OWW)      // 12288 per-sample R elements
#define RTOT (BATCH*RPS)       // 393216
#define CANDCAP 32768
#define NW 24576               // weight elements 128*3*8*8
#define WSEG 102               // write_k segments of 1024 float4 per sample

// ---------------------------------------------------------------------------
// Prep (once): weight f64 layouts + Rd = -Y init, fused into one launch.
// WDd [a][kh][c][kw] (convD); Wt2d[c][i][j][a] (convDt, 8 f64 contiguous per
// (c,i,j,atom-group) -> wave-uniform s_load_dwordx16).
// ---------------------------------------------------------------------------
__global__ __launch_bounds__(256) void prep_k(const float* __restrict__ Wg,
    double* __restrict__ WDd, double* __restrict__ Wt2d,
    const float* __restrict__ Y, double* __restrict__ Rd) {
  int e = blockIdx.x * 256 + threadIdx.x;
  if (e < NW) {
    {
      int kw = e & 7; int t = e >> 3; int c = t % 3; t /= 3; int kh = t & 7; int a = t >> 3;
      WDd[e] = (double)Wg[(a*3 + c)*64 + kh*8 + kw];
    }
    {
      int a = e & 127; int t = e >> 7; int j = t & 7; int i = (t >> 3) & 7; int c = t >> 6;
      Wt2d[e] = (double)Wg[(a*3 + c)*64 + j*8 + i];
    }
  }
  if (e < RTOT) Rd[e] = -(double)Y[e];
}

// ---------------------------------------------------------------------------
// DENSE R += D(X) (iteration 0 only). Block = (b, 4-row band, atom-QUARTER).
// grid = 2048: 32 samples x 16 bands x 4 quarters. Atom split adds no halo
// redundancy (r7 lesson); 4-row band keeps halo at 11/4 = 2.75x.
// 4 chunks x 8 atoms staged in LDS (25.3KB -> 6 blocks/CU); wave handles
// 2 atoms/chunk; acc[4][3] f64 (24 VGPR). 4 contributors per Rd address.
// ---------------------------------------------------------------------------
__global__ __launch_bounds__(256) void convD_k(const float* __restrict__ X,
    const double* __restrict__ WDd, double* __restrict__ Rd) {
  __shared__ float Xs[8][11][72];             // 25344 B
  int p = blockIdx.x;
  int lg = (p & 7) * 256 + (p >> 3);          // bijective: 2048 = 8*256
  int b = lg >> 6; int rem = lg & 63;
  int band = rem >> 2, quarter = rem & 3;
  int row0 = band * 4;
  int a_base = quarter * 32;
  int tid = threadIdx.x;
  int ox = tid & 63;
  int wv = __builtin_amdgcn_readfirstlane(tid >> 6);
  const float* Xb = X + (size_t)b * NPS;

  double acc[4][3];
#pragma unroll
  for (int ty = 0; ty < 4; ++ty)
#pragma unroll
    for (int c = 0; c < 3; ++c) acc[ty][c] = 0.0;

  for (int ch = 0; ch < 4; ++ch) {
    __syncthreads();
    for (int e = tid; e < 8 * 11 * 72; e += 256) {
      int ai = e / 792; int rem2 = e - ai * 792;
      int r = rem2 / 72; int ss = rem2 - r * 72;
      int gy = row0 - 7 + r;
      int xcol = ss - 7;
      int a = a_base + ch * 8 + ai;
      float v = 0.0f;
      if ((unsigned)xcol < (unsigned)XW && (unsigned)gy < (unsigned)XH)
        v = Xb[a * PIX + gy * XW + xcol];
      Xs[ai][r][ss] = v;
    }
    __syncthreads();
#pragma unroll
    for (int jj = 0; jj < 2; ++jj) {
      int ai = (wv << 1) + jj;
      int a  = a_base + ch * 8 + ai;
      const double* Wa = WDd + a * 192;       // [kh][c][kw]
#pragma unroll
      for (int r = 0; r < 11; ++r) {
        int gy = row0 - 7 + r;
        if ((unsigned)gy >= (unsigned)XH) continue;   // uniform
        double xd[8];
#pragma unroll
        for (int t = 0; t < 8; ++t) xd[t] = (double)Xs[ai][r][ox + t];
#pragma unroll
        for (int ty = 0; ty < 4; ++ty) {
          int kh = ty + 7 - r;
          if ((unsigned)kh < 8u) {
            const double* Wk = Wa + kh * 24;
#pragma unroll
            for (int kw = 0; kw < 8; ++kw) {
              acc[ty][0] = fma(xd[7 - kw], Wk[kw],      acc[ty][0]);
              acc[ty][1] = fma(xd[7 - kw], Wk[8 + kw],  acc[ty][1]);
              acc[ty][2] = fma(xd[7 - kw], Wk[16 + kw], acc[ty][2]);
            }
          }
        }
      }
    }
  }
#pragma unroll
  for (int ty = 0; ty < 4; ++ty) {
    int oy = row0 + ty;
#pragma unroll
    for (int c = 0; c < 3; ++c)
      atomicAdd(&Rd[((size_t)(b * CCH + c) << 12) + (oy << 6) + ox], acc[ty][c]);
  }
}

// ---------------------------------------------------------------------------
// SPARSE R = D(X) - Y (iterations 1,2). Unchanged from round 7.
// ---------------------------------------------------------------------------
__global__ __launch_bounds__(256) void convD_sparse_k(const float* __restrict__ Wg,
    const int* __restrict__ nzidx, const float* __restrict__ nzval,
    const float* __restrict__ Y, float* __restrict__ R) {
  __shared__ double accd[512];       // [rr][ox]
  __shared__ float Wf[8192];         // [a][kh][kw] for this c
  __shared__ int   li[KSEL];
  __shared__ float lv[KSEL];
  int p = blockIdx.x;
  int lg = (p & 7) * 96 + (p >> 3);  // bijective: 768 = 8*96
  int s = lg / 24; int r = lg % 24; int c = r >> 3; int band = r & 7;
  int row0 = band * 8;
  int tid = threadIdx.x;
  for (int e = tid; e < 512; e += 256) accd[e] = 0.0;
  for (int e = tid; e < 8192; e += 256) {
    int a = e >> 6, k2 = e & 63;
    Wf[e] = Wg[(a * 3 + c) * 64 + k2];
  }
  for (int e = tid; e < KSEL; e += 256) {
    li[e] = nzidx[s * KSEL + e];
    lv[e] = nzval[s * KSEL + e];
  }
  __syncthreads();
  int slot = tid >> 3, kw = tid & 7;
  for (int e = slot; e < KSEL; e += 32) {
    int idx = li[e];
    int a = (int)((unsigned)idx / 3249u);
    int pp = idx - a * 3249;
    int y = (int)((unsigned)pp / 57u);
    int x = pp - y * 57;
    int dy = y - row0;
    if (dy < -7 || dy > 7) continue;
    double val = (double)lv[e];
    const float* wp = Wf + (a << 6) + kw;
#pragma unroll
    for (int kh = 0; kh < 8; ++kh) {
      int rr = dy + kh;
      if ((unsigned)rr < 8u)
        __hip_atomic_fetch_add(&accd[(rr << 6) + x + kw],
                               val * (double)wp[kh << 3],
                               __ATOMIC_RELAXED, __HIP_MEMORY_SCOPE_WORKGROUP);
    }
  }
  __syncthreads();
  const float* Yb = Y + (((size_t)(s * CCH + c)) << 12) + (row0 << 6);
  float* Rb = R + (((size_t)(s * CCH + c)) << 12) + (row0 << 6);
  for (int e = tid; e < 512; e += 256)
    Rb[e] = (float)(accd[e] - (double)Yb[e]);
}

// ---------------------------------------------------------------------------
// HT = Xprev - Dt(R), f64, fused level-1 hist. Templated on R's type:
// it=0 reads Rd (f64) directly -- (float)Rd[i] is bit-identical to the old
// rfin output, so numerics unchanged; kills the rfin pass + launch.
// ---------------------------------------------------------------------------
template <typename TR>
__global__ __launch_bounds__(256) void convDt_k(const TR* __restrict__ R,
    const double* __restrict__ Wt2d, const float* __restrict__ Xprev,
    float* __restrict__ HT, unsigned* __restrict__ g1) {
  __shared__ float Rl[3][15][72];
  __shared__ unsigned hh[1024];      // packed: 2 u16 bins per word
  int p = blockIdx.x;
  int lg = (p & 7) * 512 + (p >> 3);  // bijective: 4096 = 8*512
  int b = lg >> 7; int rem = lg & 127; int ag = rem >> 3; int by = rem & 7;
  int row0 = by * 8;
  int a0 = ag * 8;
  int tid = threadIdx.x;
  for (int e = tid; e < 1024; e += 256) hh[e] = 0;
  for (int e = tid; e < 3 * 15 * 72; e += 256) {
    int c = e / (15 * 72); int r2 = e - c * (15 * 72);
    int rr = r2 / 72; int cc = r2 - rr * 72;
    int gr = row0 + rr;
    float v = 0.0f;
    if (cc < OWW && gr < OHH)
      v = (float)R[((size_t)(b * CCH + c) << 12) + (gr << 6) + cc];
    Rl[c][rr][cc] = v;
  }
  __syncthreads();
  int x = tid & 63, yg = tid >> 6;
  int yb = yg * 2;
  double acc[8][2];
#pragma unroll
  for (int aa = 0; aa < 8; ++aa) { acc[aa][0] = 0.0; acc[aa][1] = 0.0; }

#pragma unroll 1
  for (int c = 0; c < 3; ++c) {
#pragma unroll 1
    for (int j = 0; j < 8; ++j) {
      double rw[9];
#pragma unroll
      for (int r = 0; r < 9; ++r) rw[r] = (double)Rl[c][yb + r][x + j];
#pragma unroll
      for (int i = 0; i < 8; ++i) {
        const double* wp = Wt2d + ((c * 8 + i) * 8 + j) * 128 + a0;  // uniform
#pragma unroll
        for (int aa = 0; aa < 8; ++aa) {
          double w = wp[aa];
          acc[aa][0] = fma(rw[i + 0], w, acc[aa][0]);
          acc[aa][1] = fma(rw[i + 1], w, acc[aa][1]);
        }
      }
    }
  }
  if (x < XW) {
#pragma unroll
    for (int ty = 0; ty < 2; ++ty) {
      int yy = row0 + yb + ty;
      if (yy < XH) {
#pragma unroll
        for (int aa = 0; aa < 8; ++aa) {
          size_t xo = (size_t)(b * ATOMS + a0 + aa) * PIX + yy * XW + x;
          float fv = (float)((double)Xprev[xo] - acc[aa][ty]);
          HT[xo] = fv;
          unsigned u = __float_as_uint(fv) & 0x7fffffffu;
          unsigned bin = u >> 20;
          atomicAdd(&hh[bin >> 1], 1u << ((bin & 1) << 4));
        }
      }
    }
  }
  __syncthreads();
  unsigned* gp = g1 + (size_t)b * 2048;
  for (int e = tid; e < 1024; e += 256) {
    unsigned v = hh[e];
    unsigned lo = v & 0xffffu, hi = v >> 16;
    if (lo) atomicAdd(&gp[2 * e], lo);
    if (hi) atomicAdd(&gp[2 * e + 1], hi);
  }
}

// Find bin containing rank Kv (descending); Kin==nullptr -> KSEL.
template <int NB>
__global__ __launch_bounds__(256) void find_k(const unsigned* __restrict__ gh,
    const int* __restrict__ Kin, int* __restrict__ Bout, int* __restrict__ Kout) {
  int s = blockIdx.x;
  const unsigned* h = gh + s * NB;
  __shared__ unsigned part[256];
  constexpr int C = NB / 256;
  int t = threadIdx.x;
  unsigned sum = 0;
#pragma unroll
  for (int e = 0; e < C; ++e) sum += h[t * C + e];
  part[t] = sum;
  __syncthreads();
  if (t == 0) {
    int Kv = Kin ? Kin[s] : KSEL;
    unsigned cumBefore = 0;
    int bsel = 0;
    for (int q = 255; q >= 0; --q) {
      unsigned ps = part[q];
      if ((int)(cumBefore + ps) >= Kv) {
        for (int e = q * C + C - 1;; --e) {
          unsigned c2 = cumBefore + h[e];
          if ((int)c2 >= Kv) { bsel = e; break; }
          cumBefore = c2;
        }
        break;
      }
      cumBefore += ps;
    }
    Bout[s] = bsel;
    Kout[s] = Kv - (int)cumBefore;
  }
}

// ---------------------------------------------------------------------------
// Level 2: float4 scan; per-block LDS candidate aggregation (one global
// atomic per block). Unchanged from round 7.
// ---------------------------------------------------------------------------
__global__ __launch_bounds__(256) void hist2_k(const float* __restrict__ HT,
    const int* __restrict__ b1, unsigned* __restrict__ g2,
    int* __restrict__ cand, int* __restrict__ candcnt) {
  __shared__ unsigned h[1024];
  __shared__ int lidx[4096];
  __shared__ int lcnt, lbase;
  for (int e = threadIdx.x; e < 1024; e += 256) h[e] = 0;
  if (threadIdx.x == 0) lcnt = 0;
  __syncthreads();
  int s = blockIdx.x >> 5;
  int chunk = blockIdx.x & 31;
  unsigned pre = (unsigned)b1[s];
  const uint4* U4 = (const uint4*)(HT + (size_t)s * NPS);
  for (int i4 = chunk * 256 + threadIdx.x; i4 < NPS / 4; i4 += 32 * 256) {
    uint4 v = U4[i4];
    unsigned uu[4] = {v.x, v.y, v.z, v.w};
#pragma unroll
    for (int t = 0; t < 4; ++t) {
      unsigned u = uu[t] & 0x7fffffffu;
      if ((u >> 20) == pre) {
        atomicAdd(&h[(u >> 10) & 1023], 1u);
        int pos = atomicAdd(&lcnt, 1);           // LDS atomic, cheap
        if (pos < 4096) lidx[pos] = i4 * 4 + t;
      }
    }
  }
  __syncthreads();
  if (threadIdx.x == 0) {
    int n = lcnt < 4096 ? lcnt : 4096;
    lbase = atomicAdd(&candcnt[s], n);           // ONE global atomic/block
  }
  __syncthreads();
  int n = lcnt < 4096 ? lcnt : 4096;
  int base = lbase;
  for (int e = threadIdx.x; e < n; e += 256) {
    int g = base + e;
    if (g < CANDCAP) cand[s * CANDCAP + g] = lidx[e];
  }
  for (int e = threadIdx.x; e < 1024; e += 256)
    if (h[e]) atomicAdd(&g2[s * 1024 + e], h[e]);
}

// ---------------------------------------------------------------------------
// Fused level-2 rank find + level 3 + tie resolution (one block per sample).
// Unchanged from round 7.
// ---------------------------------------------------------------------------
__global__ __launch_bounds__(256) void pass3_k(const float* __restrict__ HT,
    const int* __restrict__ cand, const int* __restrict__ candcnt,
    const int* __restrict__ b1, const unsigned* __restrict__ g2,
    const int* __restrict__ k1, unsigned* __restrict__ tau_out,
    int* __restrict__ cutoff_out) {
  int s = blockIdx.x;
  __shared__ unsigned h[1024];
  __shared__ unsigned part[256];
  __shared__ int eqidx[1024];
  __shared__ int eqn;
  __shared__ unsigned tau_sh;
  __shared__ int k3_sh;
  __shared__ int b2_sh, k2_sh;
  int t = threadIdx.x;
  const unsigned* hg = g2 + s * 1024;
  unsigned sum = 0;
#pragma unroll
  for (int e = 0; e < 4; ++e) sum += hg[t * 4 + e];
  part[t] = sum;
  for (int e = t; e < 1024; e += 256) h[e] = 0;
  if (t == 0) eqn = 0;
  __syncthreads();
  if (t == 0) {
    int Kv = k1[s];
    unsigned cumBefore = 0;
    int bsel = 0;
    for (int q = 255; q >= 0; --q) {
      unsigned ps = part[q];
      if ((int)(cumBefore + ps) >= Kv) {
        for (int e = q * 4 + 3;; --e) {
          unsigned c2 = cumBefore + hg[e];
          if ((int)c2 >= Kv) { bsel = e; break; }
          cumBefore = c2;
        }
        break;
      }
      cumBefore += ps;
    }
    b2_sh = bsel;
    k2_sh = Kv - (int)cumBefore;
  }
  __syncthreads();
  int n = candcnt[s];
  if (n > CANDCAP) n = CANDCAP;
  unsigned pre21 = (((unsigned)b1[s]) << 10) | (unsigned)b2_sh;
  const unsigned* U = (const unsigned*)(HT + (size_t)s * NPS);
  for (int e = t; e < n; e += 256) {
    int i = cand[s * CANDCAP + e];
    unsigned u = U[i] & 0x7fffffffu;
    if ((u >> 10) == pre21) atomicAdd(&h[u & 1023], 1u);
  }
  __syncthreads();
  if (t == 0) {
    int Kv = k2_sh;
    unsigned cumBefore = 0;
    int b3 = 0;
    for (int e = 1023; e >= 0; --e) {
      unsigned c2 = cumBefore + h[e];
      if ((int)c2 >= Kv) { b3 = e; break; }
      cumBefore = c2;
    }
    tau_sh = (pre21 << 10) | (unsigned)b3;
    k3_sh = Kv - (int)cumBefore;
  }
  __syncthreads();
  unsigned tau = tau_sh;
  for (int e = t; e < n; e += 256) {
    int i = cand[s * CANDCAP + e];
    unsigned u = U[i] & 0x7fffffffu;
    if (u == tau) {
      int pos = atomicAdd(&eqn, 1);
      if (pos < 1024) eqidx[pos] = i;
    }
  }
  __syncthreads();
  if (t == 0) {
    int m = eqn < 1024 ? eqn : 1024;
    int k3 = k3_sh;
    int cutoff;
    if (k3 >= m) {
      cutoff = 0x7fffffff;
    } else {
      int last = -1;
      for (int r = 0; r < k3; ++r) {
        int mn = 0x7fffffff;
        for (int q = 0; q < m; ++q) {
          int v = eqidx[q];
          if (v > last && v < mn) mn = v;
        }
        last = mn;
      }
      cutoff = last;
    }
    tau_out[s] = tau;
    cutoff_out[s] = cutoff;
  }
}

// ---------------------------------------------------------------------------
// Threshold write (float4) + optional nz-list emit (skipped on the last
// iteration: nzidx==nullptr), per-block LDS aggregation.
// ---------------------------------------------------------------------------
__global__ __launch_bounds__(256) void write_k(const float* __restrict__ HT,
    const unsigned* __restrict__ tau, const int* __restrict__ cutoff,
    float* __restrict__ Xo, int* __restrict__ nzidx, float* __restrict__ nzval,
    int* __restrict__ nzcnt) {
  __shared__ int lidx[2048];
  __shared__ float lval[2048];
  __shared__ int lcnt, lbase;
  int s = blockIdx.x / WSEG;
  int seg = blockIdx.x % WSEG;
  int tid = threadIdx.x;
  bool emit = (nzidx != nullptr);
  if (tid == 0) lcnt = 0;
  __syncthreads();
  unsigned tt = tau[s];
  int co = cutoff[s];
  size_t sbase = (size_t)s * NPS;
  const float4* H4 = (const float4*)(HT + sbase);
  float4* X4 = (float4*)(Xo + sbase);
  int f0 = seg * 1024;
#pragma unroll
  for (int rr = 0; rr < 4; ++rr) {
    int i4 = f0 + rr * 256 + tid;
    if (i4 < NPS / 4) {
      float4 v = H4[i4];
      float vv[4] = {v.x, v.y, v.z, v.w};
      float oo[4];
#pragma unroll
      for (int t = 0; t < 4; ++t) {
        int il = i4 * 4 + t;
        unsigned u = __float_as_uint(vv[t]) & 0x7fffffffu;
        bool keep = (u > tt) || (u == tt && il <= co);
        oo[t] = keep ? vv[t] : 0.0f;
        if (keep && emit) {
          int pos = atomicAdd(&lcnt, 1);
          if (pos < 2048) { lidx[pos] = il; lval[pos] = vv[t]; }
        }
      }
      X4[i4] = make_float4(oo[0], oo[1], oo[2], oo[3]);
    }
  }
  if (!emit) return;
  __syncthreads();
  if (tid == 0) lbase = atomicAdd(&nzcnt[s], lcnt);
  __syncthreads();
  int n = lcnt < 2048 ? lcnt : 2048;
  int base = lbase;
  for (int e = tid; e < n; e += 256) {
    int g = base + e;
    if (g < KSEL) { nzidx[s * KSEL + g] = lidx[e]; nzval[s * KSEL + g] = lval[e]; }
  }
}

extern "C" void kernel_launch(void* const* d_in, const int* in_sizes, int n_in,
                              void* d_out, int out_size, void* d_ws, size_t ws_size,
                              hipStream_t stream) {
  const float* Y  = (const float*)d_in[0];
  const float* X0 = (const float*)d_in[1];
  const float* Wg = (const float*)d_in[2];
  float* Xout = (float*)d_out;

  double* WDd  = (double*)d_ws;                        // NW f64
  double* Wt2d = WDd + NW;                             // NW f64
  float* HT   = (float*)(Wt2d + NW);                   // NTOT f32
  float* Rbuf = HT + NTOT;                             // RTOT f32
  double* Rd  = (double*)(Rbuf + RTOT);                // RTOT f64
  unsigned* g1 = (unsigned*)(Rd + RTOT);               // 32*2048
  unsigned* g2 = g1 + 32 * 2048;                       // 32*1024
  int* candcnt = (int*)(g2 + 32 * 1024);               // 32
  int* nzcnt = candcnt + 32;                           // 32
  int* b1 = nzcnt + 32;
  int* k1 = b1 + 32;
  unsigned* tau = (unsigned*)(k1 + 32);
  int* cutoff = (int*)(tau + 32);
  int* cand = cutoff + 32;                             // 32*CANDCAP
  int* nzidx = cand + 32 * CANDCAP;                    // 32*KSEL
  float* nzval = (float*)(nzidx + 32 * KSEL);          // 32*KSEL
  size_t zero_bytes = (size_t)(32 * 2048 + 32 * 1024 + 32 + 32) * 4;

  prep_k<<<dim3((RTOT + 255) / 256), dim3(256), 0, stream>>>(Wg, WDd, Wt2d, Y, Rd);

  for (int it = 0; it < 3; ++it) {
    const float* Xsrc = (it == 0) ? X0 : (const float*)Xout;
    hipMemsetAsync(g1, 0, zero_bytes, stream);  // g1, g2, candcnt, nzcnt
    if (it == 0) {
      convD_k<<<dim3(2048), dim3(256), 0, stream>>>(Xsrc, WDd, Rd);
      convDt_k<double><<<dim3(4096), dim3(256), 0, stream>>>(Rd, Wt2d, Xsrc, HT, g1);
    } else {
      convD_sparse_k<<<dim3(BATCH * CCH * 8), dim3(256), 0, stream>>>(
          Wg, nzidx, nzval, Y, Rbuf);
      convDt_k<float><<<dim3(4096), dim3(256), 0, stream>>>(Rbuf, Wt2d, Xsrc, HT, g1);
    }
    find_k<2048><<<dim3(BATCH), dim3(256), 0, stream>>>(g1, (const int*)nullptr, b1, k1);
    hist2_k<<<dim3(BATCH * 32), dim3(256), 0, stream>>>(HT, b1, g2, cand, candcnt);
    pass3_k<<<dim3(BATCH), dim3(256), 0, stream>>>(HT, cand, candcnt, b1, g2, k1, tau, cutoff);
    bool last = (it == 2);
    write_k<<<dim3(BATCH * WSEG), dim3(256), 0, stream>>>(HT, tau, cutoff, Xout,
        last ? nullptr : nzidx, last ? nullptr : nzval, nzcnt);
  }
}